// Round 12
// baseline (966.586 us; speedup 1.0000x reference)
//
#include <hip/hip_runtime.h>
#include <math.h>

#define BB 8
#define SS 512
#define HHEAD 8
#define LLAY 4
#define KCB 1024
#define BSN 4096          // B*S
#define ROWS 49152        // BS*12
#define NEL 49152         // B*S*12

__constant__ int d_REP[12] = {0,1,2,2,3,3,4,4,5,5,6,6};

typedef __attribute__((ext_vector_type(8))) short bf16x8;
typedef __attribute__((ext_vector_type(4))) float f32x4;

// bf16 weight-region offsets (ushorts) inside wb
#define OB_W2 0
#define OB_W3 28672
#define OB_WQ 57344        // + l*28672
#define OB_WK 172032
#define OB_WV 286720
#define OB_WO 401408
#define OB_F1 516096       // + l*114688
#define OB_F2 974848
#define WB_TOTAL 1433600

__device__ inline unsigned short f2bf(float x) {
    unsigned u = __builtin_bit_cast(unsigned, x);
    u += 0x7FFF + ((u >> 16) & 1);
    return (unsigned short)(u >> 16);
}

// fast gelu: erf via Abramowitz-Stegun 7.1.26 (|err| < 1.5e-7), HW rcp
__device__ inline float fast_gelu(float a) {
    float x = a * 0.7071067811865475f;
    float ax = fabsf(x);
    float tt = __builtin_amdgcn_rcpf(fmaf(0.3275911f, ax, 1.0f));
    float poly = ((((1.061405429f * tt - 1.453152027f) * tt + 1.421413741f) * tt
                   - 0.284496736f) * tt + 0.254829592f) * tt;
    float y = fmaf(-poly, __expf(-x * x), 1.0f);
    return 0.5f * a * (1.0f + copysignf(y, x));
}

// symmetry-reduced act on one 12-vector (tables in qf[160..] / qf[256..])
__device__ inline void act12(const float* __restrict__ qf, const float v[12], float o[12]) {
    constexpr int S_[7]  = {0, 1, 2, 4, 6, 8, 10};
    constexpr int DKv[7] = {1, 1, 2, 2, 2, 2, 2};
    constexpr int P_[7]  = {1, 2, 12, 6, 4, 3, 12};
    constexpr int UO[7]  = {0, 1, 3, 15, 21, 25, 28};
    constexpr int OO[7]  = {0, 1, 3, 27, 39, 47, 53};
    const float* QP = qf + 160;
    const float* QO = qf + 256;
#pragma unroll
    for (int k = 0; k < 7; ++k) {
        float g[12];
#pragma unroll
        for (int u = 0; u < P_[k]; ++u) {
            float p = QP[(UO[k] + u) * 2] * v[S_[k]];
            if (DKv[k] == 2) p = fmaf(QP[(UO[k] + u) * 2 + 1], v[S_[k] + 1], p);
            g[u] = fast_gelu(p);
        }
#pragma unroll
        for (int d = 0; d < DKv[k]; ++d) {
            float a = 0.f;
#pragma unroll
            for (int u = 0; u < P_[k]; ++u) a = fmaf(QO[OO[k] + d * P_[k] + u], g[u], a);
            o[S_[k] + d] = a;
        }
    }
}

// ---------------- QF init + rowsums + reduced act tables ----------------
__global__ void k_init_qf(float* qf) {
    int t = threadIdx.x;
    if (t < 144) {
        int r = t / 12, j = t % 12;
        double v;
        if (r == 0)      v = 1.0 / sqrt(12.0);
        else if (r == 1) v = ((j & 1) ? -1.0 : 1.0) / sqrt(12.0);
        else {
            int m = r >> 1;
            double ang = 2.0 * 3.14159265358979323846 * (double)m * (double)j / 12.0;
            v = (((r & 1) == 0) ? cos(ang) : sin(ang)) / sqrt(6.0);
        }
        qf[t] = (float)v;
    }
    __syncthreads();
    if (t < 12) {
        float s = 0.f;
        for (int j = 0; j < 12; ++j) s += qf[t * 12 + j];
        qf[144 + t] = s;
    }
    __syncthreads();
    if (t == 0) {
        const int S_[7]  = {0, 1, 2, 4, 6, 8, 10};
        const int DKv[7] = {1, 1, 2, 2, 2, 2, 2};
        const int P_[7]  = {1, 2, 12, 6, 4, 3, 12};
        const int UO[7]  = {0, 1, 3, 15, 21, 25, 28};
        const int OO[7]  = {0, 1, 3, 27, 39, 47, 53};
        for (int k = 0; k < 7; ++k) {
            for (int u = 0; u < P_[k]; ++u) {
                qf[160 + (UO[k] + u) * 2]     = qf[S_[k] * 12 + u];
                qf[160 + (UO[k] + u) * 2 + 1] = (DKv[k] == 2) ? qf[(S_[k] + 1) * 12 + u] : 0.f;
            }
            for (int d = 0; d < DKv[k]; ++d)
                for (int u = 0; u < P_[k]; ++u) {
                    float a = 0.f;
                    for (int pp = u; pp < 12; pp += P_[k]) a += qf[(S_[k] + d) * 12 + pp];
                    qf[256 + OO[k] + d * P_[k] + u] = a;
                }
        }
    }
}

// ---------------- pe table [512][64] ----------------
__global__ void k_init_pe(float* pe) {
    int s = blockIdx.x, m = threadIdx.x;
    int i = m >> 1;
    float dv = expf((float)(2 * i) * (-0.14391156831212787f));
    float arg = (float)s * dv;
    pe[s * 64 + m] = (m & 1) ? cosf(arg) : sinf(arg);
}

// ---------------- weight bf16 pre-conversion (one half) -----------------
__global__ __launch_bounds__(256) void k_cvtw(const float* __restrict__ w2,
                                              const float* __restrict__ w3,
                                              const float* __restrict__ wq,
                                              const float* __restrict__ wk,
                                              const float* __restrict__ wv,
                                              const float* __restrict__ wo,
                                              const float* __restrict__ f1,
                                              const float* __restrict__ f2,
                                              unsigned short* __restrict__ dst) {
    int i = blockIdx.x * 256 + threadIdx.x;   // float4 index
    const float* src; int off;
    if      (i <   7168) { src = w2; off = i; }
    else if (i <  14336) { src = w3; off = i -   7168; }
    else if (i <  43008) { src = wq; off = i -  14336; }
    else if (i <  71680) { src = wk; off = i -  43008; }
    else if (i < 100352) { src = wv; off = i -  71680; }
    else if (i < 129024) { src = wo; off = i - 100352; }
    else if (i < 243712) { src = f1; off = i - 129024; }
    else if (i < 358400) { src = f2; off = i - 243712; }
    else return;
    float4 v = ((const float4*)src)[off];
    ushort4 u = {f2bf(v.x), f2bf(v.y), f2bf(v.z), f2bf(v.w)};
    *(ushort4*)(dst + (size_t)i * 4) = u;
}

// ---------------- fused embed + act64: 4 bs per block -------------------
__global__ __launch_bounds__(256) void k_embact(const float* __restrict__ x,
                                                const float* __restrict__ fb,
                                                const float* __restrict__ fw,
                                                const float* __restrict__ w1,
                                                const float* __restrict__ qf,
                                                float* __restrict__ out) {
    int bs0 = blockIdx.x * 4;
    int t = threadIdx.x;
    __shared__ float xs[4][12], h1[4][12];
    if (t < 48) {
        int sb = t / 12, j = t % 12;
        xs[sb][j] = x[(bs0 + sb) * 12 + j] + fb[0];
    }
    __syncthreads();
    if (t < 48) {
        int sb = t / 12, j = t % 12;
        float a = 0.f;
        for (int p = 0; p < 12; ++p) a += qf[j * 12 + p] * xs[sb][p];
        h1[sb][j] = a * fw[0];
    }
    __syncthreads();
    int sb = t >> 6, m = t & 63;
    float v[12], o[12];
#pragma unroll
    for (int d = 0; d < 12; ++d) v[d] = h1[sb][d] * w1[d_REP[d] * 64 + m];
    act12(qf, v, o);
    float* ob = out + ((size_t)(bs0 + sb) * 12) * 64 + m;
#pragma unroll
    for (int d = 0; d < 12; ++d) ob[d * 64] = o[d];
}

// ---------------- act standalone (t1, mdim=64) --------------------------
__global__ __launch_bounds__(256) void k_act(float* __restrict__ h,
                                             const float* __restrict__ qf) {
    int idx = blockIdx.x * 256 + threadIdx.x;
    if (idx >= BSN * 64) return;
    int bs = idx >> 6, m = idx & 63;
    float* base = h + (size_t)bs * 12 * 64 + m;
    float v[12], o[12];
#pragma unroll
    for (int d = 0; d < 12; ++d) v[d] = base[d * 64];
    act12(qf, v, o);
#pragma unroll
    for (int d = 0; d < 12; ++d) base[d * 64] = o[d];
}

// ---------------- MFMA bf16 lin (A fp32, B bf16). PE also writes hb -----
template <int PE>
__global__ __launch_bounds__(256) void k_lin4(const float* __restrict__ in,
                                              const unsigned short* __restrict__ Wb,
                                              const float* __restrict__ qfp,
                                              const float* __restrict__ pe,
                                              float* __restrict__ outv,
                                              unsigned short* __restrict__ hb) {
    const int d   = blockIdx.x;
    const int bs0 = blockIdx.y * 64;
    __shared__ unsigned short sA[64 * 72];
    __shared__ unsigned short sB[64 * 72];
    const int t  = threadIdx.x;
    const int w  = t >> 6;
    const int l  = t & 63;
    const int lr = l & 15;
    const int lk = l >> 4;

    f32x4 acc[4];
#pragma unroll
    for (int f = 0; f < 4; ++f) acc[f] = (f32x4){0.f, 0.f, 0.f, 0.f};

    const unsigned short* wbase = Wb + (size_t)d_REP[d] * 64 * 64;

    for (int e = t; e < 1024; e += 256) {
        int r = e >> 4, qq = e & 15;
        float4 v = *(const float4*)(in + ((size_t)(bs0 + r) * 12 + d) * 64 + qq * 4);
        ushort4 u = {f2bf(v.x), f2bf(v.y), f2bf(v.z), f2bf(v.w)};
        *(ushort4*)&sA[r * 72 + qq * 4] = u;
    }
    for (int e = t; e < 512; e += 256) {
        int c = e >> 3, seg = e & 7;
        *(bf16x8*)&sB[c * 72 + seg * 8] = *(const bf16x8*)(wbase + c * 64 + seg * 8);
    }
    __syncthreads();
#pragma unroll
    for (int ks = 0; ks < 2; ++ks) {
        bf16x8 a = *(const bf16x8*)&sA[(w * 16 + lr) * 72 + ks * 32 + lk * 8];
#pragma unroll
        for (int f = 0; f < 4; ++f) {
            bf16x8 b = *(const bf16x8*)&sB[(f * 16 + lr) * 72 + ks * 32 + lk * 8];
            acc[f] = __builtin_amdgcn_mfma_f32_16x16x32_bf16(a, b, acc[f], 0, 0, 0);
        }
    }

#pragma unroll
    for (int f = 0; f < 4; ++f) {
#pragma unroll
        for (int reg = 0; reg < 4; ++reg) {
            int bs = bs0 + w * 16 + lk * 4 + reg;
            int o  = f * 16 + lr;
            float val = acc[f][reg];
            size_t row = (size_t)bs * 12 + d;
            if (PE) val += qfp[144 + d] * pe[(bs & 511) * 64 + o];
            outv[row * 64 + o] = val;
            if (PE) hb[row * 64 + o] = f2bf(val);
        }
    }
}

// ---------------- wo-GEMM: A bf16 (attn out), B bf16, h +=, hb out ------
__global__ __launch_bounds__(256) void k_linwo(const unsigned short* __restrict__ t1b,
                                               const unsigned short* __restrict__ Wb,
                                               float* __restrict__ h,
                                               unsigned short* __restrict__ hb) {
    const int d   = blockIdx.x;
    const int bs0 = blockIdx.y * 64;
    __shared__ unsigned short sA[64 * 72];
    __shared__ unsigned short sB[64 * 72];
    const int t  = threadIdx.x;
    const int w  = t >> 6;
    const int l  = t & 63;
    const int lr = l & 15;
    const int lk = l >> 4;

    f32x4 acc[4];
#pragma unroll
    for (int f = 0; f < 4; ++f) acc[f] = (f32x4){0.f, 0.f, 0.f, 0.f};

    const unsigned short* wbase = Wb + (size_t)d_REP[d] * 64 * 64;

    for (int e = t; e < 512; e += 256) {
        int r = e >> 3, seg = e & 7;
        *(bf16x8*)&sA[r * 72 + seg * 8] =
            *(const bf16x8*)(t1b + ((size_t)(bs0 + r) * 12 + d) * 64 + seg * 8);
    }
    for (int e = t; e < 512; e += 256) {
        int c = e >> 3, seg = e & 7;
        *(bf16x8*)&sB[c * 72 + seg * 8] = *(const bf16x8*)(wbase + c * 64 + seg * 8);
    }
    __syncthreads();
#pragma unroll
    for (int ks = 0; ks < 2; ++ks) {
        bf16x8 a = *(const bf16x8*)&sA[(w * 16 + lr) * 72 + ks * 32 + lk * 8];
#pragma unroll
        for (int f = 0; f < 4; ++f) {
            bf16x8 b = *(const bf16x8*)&sB[(f * 16 + lr) * 72 + ks * 32 + lk * 8];
            acc[f] = __builtin_amdgcn_mfma_f32_16x16x32_bf16(a, b, acc[f], 0, 0, 0);
        }
    }

#pragma unroll
    for (int f = 0; f < 4; ++f) {
#pragma unroll
        for (int reg = 0; reg < 4; ++reg) {
            int bs = bs0 + w * 16 + lk * 4 + reg;
            int o  = f * 16 + lr;
            size_t row = (size_t)bs * 12 + d;
            float val = acc[f][reg] + h[row * 64 + o];
            h[row * 64 + o] = val;
            hb[row * 64 + o] = f2bf(val);
        }
    }
}

// ---------------- QKV projection (A = hb bf16, B bf16) ------------------
__global__ __launch_bounds__(256) void k_linqkv(const unsigned short* __restrict__ hbin,
                                                const unsigned short* __restrict__ wq,
                                                const unsigned short* __restrict__ wk,
                                                const unsigned short* __restrict__ wv,
                                                unsigned short* __restrict__ oq,
                                                unsigned short* __restrict__ ok,
                                                unsigned short* __restrict__ ov) {
    const int d   = blockIdx.x;
    const int bs0 = blockIdx.y * 64;
    __shared__ unsigned short sA[64 * 72];
    __shared__ unsigned short sB[64 * 72];
    const int t  = threadIdx.x;
    const int w  = t >> 6;
    const int l  = t & 63;
    const int lr = l & 15;
    const int lk = l >> 4;
    const int rep = d_REP[d];

    for (int e = t; e < 512; e += 256) {
        int r = e >> 3, seg = e & 7;
        *(bf16x8*)&sA[r * 72 + seg * 8] =
            *(const bf16x8*)(hbin + ((size_t)(bs0 + r) * 12 + d) * 64 + seg * 8);
    }

    for (int part = 0; part < 3; ++part) {
        const unsigned short* wsel = (part == 0) ? wq : (part == 1) ? wk : wv;
        const unsigned short* wbase = wsel + (size_t)rep * 64 * 64;
        __syncthreads();
        for (int e = t; e < 512; e += 256) {
            int c = e >> 3, seg = e & 7;
            *(bf16x8*)&sB[c * 72 + seg * 8] = *(const bf16x8*)(wbase + c * 64 + seg * 8);
        }
        __syncthreads();
        f32x4 acc[4];
#pragma unroll
        for (int f = 0; f < 4; ++f) acc[f] = (f32x4){0.f, 0.f, 0.f, 0.f};
#pragma unroll
        for (int ks = 0; ks < 2; ++ks) {
            bf16x8 a = *(const bf16x8*)&sA[(w * 16 + lr) * 72 + ks * 32 + lk * 8];
#pragma unroll
            for (int f = 0; f < 4; ++f) {
                bf16x8 b = *(const bf16x8*)&sB[(f * 16 + lr) * 72 + ks * 32 + lk * 8];
                acc[f] = __builtin_amdgcn_mfma_f32_16x16x32_bf16(a, b, acc[f], 0, 0, 0);
            }
        }
        unsigned short* oh = (part == 0) ? oq : (part == 1) ? ok : ov;
#pragma unroll
        for (int f = 0; f < 4; ++f) {
#pragma unroll
            for (int reg = 0; reg < 4; ++reg) {
                int bs = bs0 + w * 16 + lk * 4 + reg;
                int o  = f * 16 + lr;
                int b = bs >> 9, s = bs & 511;
                unsigned short hv = f2bf(acc[f][reg]);
                if (part < 2)
                    oh[(((size_t)(b * 8 + (o >> 3)) * 512 + s) * 96) + d * 8 + (o & 7)] = hv;
                else
                    oh[(((size_t)(b * 8 + (o >> 3)) * 96 + d * 8 + (o & 7)) * 512) + s] = hv;
            }
        }
    }
}

// ---------------- attention v5: 64 q-rows, no-max softmax, bf16 out -----
__global__ __launch_bounds__(256) void k_attn5(const unsigned short* __restrict__ qh,
                                               const unsigned short* __restrict__ kh,
                                               const unsigned short* __restrict__ vt,
                                               unsigned short* __restrict__ out) {
    __shared__ unsigned short sK[64 * 104];
    __shared__ unsigned short sV[96 * 72];
    __shared__ unsigned short ps[4][16 * 72];
    const int bh = blockIdx.x >> 3;
    const int q0 = (blockIdx.x & 7) * 64;
    const int t = threadIdx.x;
    const int w = t >> 6;
    const int l = t & 63;
    const int lr = l & 15;
    const int lk = l >> 4;

    const unsigned short* qg = qh + ((size_t)bh * 512 + q0 + w * 16) * 96;
    bf16x8 qa[3];
#pragma unroll
    for (int ks = 0; ks < 3; ++ks)
        qa[ks] = *(const bf16x8*)(qg + (size_t)lr * 96 + ks * 32 + lk * 8);

    float ts[4] = {0.f, 0.f, 0.f, 0.f};
    f32x4 o[6];
#pragma unroll
    for (int f = 0; f < 6; ++f) o[f] = (f32x4){0.f, 0.f, 0.f, 0.f};

    const unsigned short* kg = kh + (size_t)bh * 512 * 96;
    const unsigned short* vg = vt + (size_t)bh * 96 * 512;
    const float scale = 0.10206207261596577f;   // 1/sqrt(96)

    for (int tile = 0; tile < 8; ++tile) {
        __syncthreads();
        for (int e = t; e < 768; e += 256) {
            int row = e / 12, seg = e % 12;
            *(bf16x8*)&sK[row * 104 + seg * 8] =
                *(const bf16x8*)(kg + ((size_t)(tile * 64 + row)) * 96 + seg * 8);
        }
        for (int e = t; e < 768; e += 256) {
            int row = e / 8, seg = e % 8;
            *(bf16x8*)&sV[row * 72 + seg * 8] =
                *(const bf16x8*)(vg + (size_t)row * 512 + tile * 64 + seg * 8);
        }
        __syncthreads();

#pragma unroll
        for (int f = 0; f < 4; ++f) {
            f32x4 acc = {0.f, 0.f, 0.f, 0.f};
#pragma unroll
            for (int ks = 0; ks < 3; ++ks) {
                bf16x8 kb = *(const bf16x8*)&sK[(f * 16 + lr) * 104 + ks * 32 + lk * 8];
                acc = __builtin_amdgcn_mfma_f32_16x16x32_bf16(qa[ks], kb, acc, 0, 0, 0);
            }
#pragma unroll
            for (int r = 0; r < 4; ++r) {
                float p = __expf(acc[r] * scale);
                ts[r] += p;
                ps[w][(lk * 4 + r) * 72 + f * 16 + lr] = f2bf(p);
            }
        }

        bf16x8 pa[2];
#pragma unroll
        for (int ks = 0; ks < 2; ++ks)
            pa[ks] = *(const bf16x8*)&ps[w][lr * 72 + ks * 32 + lk * 8];
#pragma unroll
        for (int f = 0; f < 6; ++f) {
            f32x4 acc = o[f];
#pragma unroll
            for (int ks = 0; ks < 2; ++ks) {
                bf16x8 vb = *(const bf16x8*)&sV[(f * 16 + lr) * 72 + ks * 32 + lk * 8];
                acc = __builtin_amdgcn_mfma_f32_16x16x32_bf16(pa[ks], vb, acc, 0, 0, 0);
            }
            o[f] = acc;
        }
    }

    float inv[4];
#pragma unroll
    for (int r = 0; r < 4; ++r) {
        float s2 = ts[r];
#pragma unroll
        for (int d = 1; d < 16; d <<= 1) s2 += __shfl_xor(s2, d);
        inv[r] = 1.0f / s2;
    }
    const int b = bh >> 3, hh = bh & 7;
#pragma unroll
    for (int r = 0; r < 4; ++r) {
        int s = q0 + w * 16 + lk * 4 + r;
        unsigned short* ob = out + ((size_t)(b * 512 + s) * 12) * 64 + hh * 8;
#pragma unroll
        for (int f = 0; f < 6; ++f) {
            int col = f * 16 + lr;
            ob[(col >> 3) * 64 + (col & 7)] = f2bf(o[f][r] * inv[r]);
        }
    }
}

// ---------------- fused f1-GEMM + act -> bf16 fmid (v4) -----------------
// A fragments loaded DIRECTLY from hb (bf16, L2) — no A-LDS, no A barriers.
__global__ __launch_bounds__(256, 4) void k_f1act(const unsigned short* __restrict__ hb,
                                                  const unsigned short* __restrict__ f1wb,
                                                  const float* __restrict__ qf,
                                                  unsigned short* __restrict__ fmidb) {
    constexpr int S_[7]  = {0, 1, 2, 4, 6, 8, 10};
    constexpr int DKv[7] = {1, 1, 2, 2, 2, 2, 2};
    const int bs0 = blockIdx.x * 16;
    const int c0  = blockIdx.y * 64;
    __shared__ unsigned short sB[64 * 72];
    const int t  = threadIdx.x;
    const int w  = t >> 6;      // wave = col fragment
    const int l  = t & 63;
    const int lr = l & 15;
    const int lk = l >> 4;

    f32x4 acc[12];
#pragma unroll
    for (int d = 0; d < 12; ++d) acc[d] = (f32x4){0.f, 0.f, 0.f, 0.f};

    const unsigned short* arow = hb + (size_t)(bs0 + lr) * 12 * 64 + lk * 8;

#pragma unroll
    for (int k = 0; k < 7; ++k) {
        if (k) __syncthreads();
        const unsigned short* wbase = f1wb + ((size_t)k * 256 + c0) * 64;
        for (int e = t; e < 512; e += 256) {
            int c = e >> 3, seg = e & 7;
            *(bf16x8*)&sB[c * 72 + seg * 8] = *(const bf16x8*)(wbase + c * 64 + seg * 8);
        }
        __syncthreads();
#pragma unroll
        for (int dd = 0; dd < 2; ++dd) {
            if (dd < DKv[k]) {
                int d = S_[k] + dd;
#pragma unroll
                for (int ks = 0; ks < 2; ++ks) {
                    bf16x8 a = *(const bf16x8*)(arow + (size_t)d * 64 + ks * 32);
                    bf16x8 b = *(const bf16x8*)&sB[(w * 16 + lr) * 72 + ks * 32 + lk * 8];
                    acc[d] = __builtin_amdgcn_mfma_f32_16x16x32_bf16(a, b, acc[d], 0, 0, 0);
                }
            }
        }
    }

    // act in registers + bf16 store (no barriers in this phase)
#pragma unroll
    for (int reg = 0; reg < 4; ++reg) {
        float v[12], o[12];
#pragma unroll
        for (int d = 0; d < 12; ++d) v[d] = acc[d][reg];
        act12(qf, v, o);
        int row = bs0 + lk * 4 + reg;
        int col = c0 + w * 16 + lr;
#pragma unroll
        for (int d = 0; d < 12; ++d)
            fmidb[((size_t)row * 12 + d) * 256 + col] = f2bf(o[d]);
    }
}

// ---------------- fused f2-GEMM (+res, h out) + next-layer QKV ----------
template <int QKV>
__global__ __launch_bounds__(256) void k_f2qkv(const unsigned short* __restrict__ inb,
                                               const unsigned short* __restrict__ Wf2,
                                               const unsigned short* __restrict__ wq,
                                               const unsigned short* __restrict__ wk,
                                               const unsigned short* __restrict__ wv,
                                               float* __restrict__ h,
                                               unsigned short* __restrict__ oq,
                                               unsigned short* __restrict__ ok,
                                               unsigned short* __restrict__ ov) {
    const int d   = blockIdx.x;
    const int bs0 = blockIdx.y * 64;
    __shared__ unsigned short sA[64 * 72];
    __shared__ unsigned short sB[64 * 72];
    __shared__ unsigned short sH[64 * 72];
    const int t  = threadIdx.x;
    const int w  = t >> 6;
    const int l  = t & 63;
    const int lr = l & 15;
    const int lk = l >> 4;
    const int rep = d_REP[d];

    f32x4 acc[4];
#pragma unroll
    for (int f = 0; f < 4; ++f) acc[f] = (f32x4){0.f, 0.f, 0.f, 0.f};

    const unsigned short* wbase = Wf2 + (size_t)rep * 64 * 256;

    // phase 1: h' = fmid * f2 + h
    for (int kc = 0; kc < 256; kc += 64) {
        __syncthreads();
        for (int e = t; e < 512; e += 256) {
            int r = e >> 3, seg = e & 7;
            *(bf16x8*)&sA[r * 72 + seg * 8] =
                *(const bf16x8*)(inb + ((size_t)(bs0 + r) * 12 + d) * 256 + kc + seg * 8);
        }
        for (int e = t; e < 512; e += 256) {
            int c = e >> 3, seg = e & 7;
            *(bf16x8*)&sB[c * 72 + seg * 8] =
                *(const bf16x8*)(wbase + (size_t)c * 256 + kc + seg * 8);
        }
        __syncthreads();
#pragma unroll
        for (int ks = 0; ks < 2; ++ks) {
            bf16x8 a = *(const bf16x8*)&sA[(w * 16 + lr) * 72 + ks * 32 + lk * 8];
#pragma unroll
            for (int f = 0; f < 4; ++f) {
                bf16x8 b = *(const bf16x8*)&sB[(f * 16 + lr) * 72 + ks * 32 + lk * 8];
                acc[f] = __builtin_amdgcn_mfma_f32_16x16x32_bf16(a, b, acc[f], 0, 0, 0);
            }
        }
    }

#pragma unroll
    for (int f = 0; f < 4; ++f) {
#pragma unroll
        for (int reg = 0; reg < 4; ++reg) {
            int rloc = w * 16 + lk * 4 + reg;
            int bs = bs0 + rloc;
            int o  = f * 16 + lr;
            size_t row = (size_t)bs * 12 + d;
            float val = acc[f][reg] + h[row * 64 + o];
            h[row * 64 + o] = val;
            if (QKV) sH[rloc * 72 + o] = f2bf(val);
        }
    }

    // phase 2: QKV for the next layer from sH (wave-local rows)
    if (QKV) {
        for (int part = 0; part < 3; ++part) {
            const unsigned short* wsel = (part == 0) ? wq : (part == 1) ? wk : wv;
            const unsigned short* wb2 = wsel + (size_t)rep * 64 * 64;
            __syncthreads();
            for (int e = t; e < 512; e += 256) {
                int c = e >> 3, seg = e & 7;
                *(bf16x8*)&sB[c * 72 + seg * 8] = *(const bf16x8*)(wb2 + c * 64 + seg * 8);
            }
            __syncthreads();
            f32x4 a2[4];
#pragma unroll
            for (int f = 0; f < 4; ++f) a2[f] = (f32x4){0.f, 0.f, 0.f, 0.f};
#pragma unroll
            for (int ks = 0; ks < 2; ++ks) {
                bf16x8 a = *(const bf16x8*)&sH[(w * 16 + lr) * 72 + ks * 32 + lk * 8];
#pragma unroll
                for (int f = 0; f < 4; ++f) {
                    bf16x8 b = *(const bf16x8*)&sB[(f * 16 + lr) * 72 + ks * 32 + lk * 8];
                    a2[f] = __builtin_amdgcn_mfma_f32_16x16x32_bf16(a, b, a2[f], 0, 0, 0);
                }
            }
            unsigned short* oh = (part == 0) ? oq : (part == 1) ? ok : ov;
#pragma unroll
            for (int f = 0; f < 4; ++f) {
#pragma unroll
                for (int reg = 0; reg < 4; ++reg) {
                    int bs = bs0 + w * 16 + lk * 4 + reg;
                    int o  = f * 16 + lr;
                    int b = bs >> 9, s = bs & 511;
                    unsigned short hv = f2bf(a2[f][reg]);
                    if (part < 2)
                        oh[(((size_t)(b * 8 + (o >> 3)) * 512 + s) * 96) + d * 8 + (o & 7)] = hv;
                    else
                        oh[(((size_t)(b * 8 + (o >> 3)) * 96 + d * 8 + (o & 7)) * 512) + s] = hv;
                }
            }
        }
    }
}

// ---------------- fc_out (decoder tail) ----------------
__global__ void k_fcout(const float* __restrict__ h, const float* __restrict__ w,
                        const float* __restrict__ qf, float* __restrict__ z) {
    int bs = blockIdx.x;
    __shared__ float td[12];
    int t = threadIdx.x;
    if (t < 12) {
        const float* row = h + ((size_t)bs * 12 + t) * 64;
        const float* wr  = w + d_REP[t] * 64;
        float a = 0.f;
        for (int i = 0; i < 64; ++i) a += row[i] * wr[i];
        td[t] = a;
    }
    __syncthreads();
    if (t < 12) {
        float a = 0.f;
        for (int d = 0; d < 12; ++d) a += qf[d * 12 + t] * td[d];
        z[bs * 12 + t] = a / 7.0f;
    }
}

// ---------------- fused fc_out + VQ (encoder tail) ----------------------
__global__ __launch_bounds__(256) void k_fcvq(const float* __restrict__ h,
                                              const float* __restrict__ w,
                                              const float* __restrict__ qf,
                                              const float* __restrict__ cb,
                                              float* __restrict__ z,
                                              float* __restrict__ zvq,
                                              float* __restrict__ zst) {
    int bs = blockIdx.x;
    int t = threadIdx.x;
    __shared__ float td[12];
    __shared__ float zv[12];
    __shared__ float sb[256];
    __shared__ int   si[256];
    if (t < 12) {
        const float* row = h + ((size_t)bs * 12 + t) * 64;
        const float* wr  = w + d_REP[t] * 64;
        float a = 0.f;
        for (int i = 0; i < 64; ++i) a += row[i] * wr[i];
        td[t] = a;
    }
    __syncthreads();
    if (t < 12) {
        float a = 0.f;
        for (int d = 0; d < 12; ++d) a += qf[d * 12 + t] * td[d];
        a /= 7.0f;
        zv[t] = a;
        z[bs * 12 + t] = a;
    }
    __syncthreads();
    float zz = 0.f;
    for (int j = 0; j < 12; ++j) zz += zv[j] * zv[j];
    float best = 3.4e38f; int bi = 0x7fffffff;
    for (int c = t; c < KCB; c += 256) {
        const float* cr = cb + c * 12;
        float cc = 0.f, dot = 0.f;
        for (int j = 0; j < 12; ++j) { cc += cr[j] * cr[j]; dot += zv[j] * cr[j]; }
        float dist = zz + cc - 2.0f * dot;
        if (dist < best) { best = dist; bi = c; }
    }
    sb[t] = best; si[t] = bi; __syncthreads();
    for (int st = 128; st > 0; st >>= 1) {
        if (t < st) {
            if (sb[t + st] < sb[t] || (sb[t + st] == sb[t] && si[t + st] < si[t])) {
                sb[t] = sb[t + st]; si[t] = si[t + st];
            }
        }
        __syncthreads();
    }
    if (t < 12) {
        float c = cb[si[0] * 12 + t];
        zvq[bs * 12 + t] = c;
        float zi = zv[t];
        zst[bs * 12 + t] = (c - zi) + zi;
    }
}

// ---------------- merged losses ----------------
__global__ __launch_bounds__(256) void k_loss(const float* __restrict__ x,
                                              const float* __restrict__ logits,
                                              const float* __restrict__ z,
                                              const float* __restrict__ zvq,
                                              float* __restrict__ xr_out,
                                              float* __restrict__ p1,
                                              float* __restrict__ p2) {
    __shared__ float red[256];
    int t = threadIdx.x;
    float acc1 = 0.f, acc2 = 0.f;
    for (int i = blockIdx.x * 256 + t; i < NEL; i += gridDim.x * 256) {
        float lg = logits[i];
        float xr = 1.0f / (1.0f + expf(-lg));
        xr_out[i] = xr;
        float xi = x[i];
        float l1 = fmaxf(logf(xr), -100.0f);
        float l2 = fmaxf(logf(1.0f - xr), -100.0f);
        acc1 += xi * l1 + (1.0f - xi) * l2;
        float dd = zvq[i] - z[i];
        acc2 += dd * dd;
    }
    red[t] = acc1; __syncthreads();
    for (int st = 128; st > 0; st >>= 1) { if (t < st) red[t] += red[t + st]; __syncthreads(); }
    if (t == 0) p1[blockIdx.x] = red[0];
    __syncthreads();
    red[t] = acc2; __syncthreads();
    for (int st = 128; st > 0; st >>= 1) { if (t < st) red[t] += red[t + st]; __syncthreads(); }
    if (t == 0) p2[blockIdx.x] = red[0];
}

__global__ void k_final(const float* __restrict__ p1, const float* __restrict__ p2,
                        float* __restrict__ out) {
    if (threadIdx.x == 0) {
        float s1 = 0.f, s2 = 0.f;
        for (int i = 0; i < 96; ++i) { s1 += p1[i]; s2 += p2[i]; }
        out[NEL]     = -s1 / (float)NEL;
        out[NEL + 1] =  s2 / (float)NEL;
        out[NEL + 2] =  s2 / (float)NEL;
    }
}

// ------------------------------------------------------------------------
extern "C" void kernel_launch(void* const* d_in, const int* in_sizes, int n_in,
                              void* d_out, int out_size, void* d_ws, size_t ws_size,
                              hipStream_t stream) {
    const float* x   = (const float*)d_in[0];
    const float* efb = (const float*)d_in[1];
    const float* efw = (const float*)d_in[2];
    const float* ew1 = (const float*)d_in[3];
    const float* ew2 = (const float*)d_in[4];
    const float* ew3 = (const float*)d_in[5];
    const float* ewq = (const float*)d_in[6];
    const float* ewk = (const float*)d_in[7];
    const float* ewv = (const float*)d_in[8];
    const float* ewo = (const float*)d_in[9];
    const float* ef1 = (const float*)d_in[10];
    const float* ef2 = (const float*)d_in[11];
    const float* eow = (const float*)d_in[12];
    const float* cb  = (const float*)d_in[13];
    const float* dfb = (const float*)d_in[14];
    const float* dfw = (const float*)d_in[15];
    const float* dw1 = (const float*)d_in[16];
    const float* dw2 = (const float*)d_in[17];
    const float* dw3 = (const float*)d_in[18];
    const float* dwq = (const float*)d_in[19];
    const float* dwk = (const float*)d_in[20];
    const float* dwv = (const float*)d_in[21];
    const float* dwo = (const float*)d_in[22];
    const float* df1 = (const float*)d_in[23];
    const float* df2 = (const float*)d_in[24];
    const float* dow = (const float*)d_in[25];
    float* out = (float*)d_out;

    float* ws = (float*)d_ws;
    float* qf   = ws;                           // 512
    float* h    = ws + 512;                     // 3,145,728
    float* fmid = h + 3145728;                  // 12,582,912 region (bf16 fmid + q/kk/vv aliases)
    float* t1   = fmid + 12582912;              // 3,145,728 (fp32 head tmp; bf16 attn-out alias)
    float* z    = t1 + 3145728;
    float* zvq  = z + NEL;
    float* zst  = zvq + NEL;
    float* z2   = zst + NEL;
    float* p1   = z2 + NEL;
    float* p2   = p1 + 128;
    float* pe   = p2 + 128;                     // 32768
    unsigned short* wb = (unsigned short*)(pe + 32768);               // 1,433,600 ushorts
    unsigned short* hb = wb + WB_TOTAL;                               // 3,145,728 ushorts
    unsigned short* fmidb = (unsigned short*)fmid;                    // 12.6M ushorts
    unsigned short* q  = (unsigned short*)(fmid + 6291456);           // after fmidb
    unsigned short* kk = q + 3145728;
    unsigned short* vv = kk + 3145728;
    unsigned short* t1b = (unsigned short*)t1;

    auto run_half = [&](const float* xin, const float* fb, const float* fw,
                        const float* w1, const float* w2, const float* w3,
                        const float* wq, const float* wk, const float* wv,
                        const float* wo, const float* f1, const float* f2) {
        k_cvtw<<<1400, 256, 0, stream>>>(w2, w3, wq, wk, wv, wo, f1, f2, wb);
        k_embact<<<BSN / 4, 256, 0, stream>>>(xin, fb, fw, w1, qf, h);
        k_lin4<0><<<dim3(12, 64), 256, 0, stream>>>(h, wb + OB_W2, qf, nullptr, t1, nullptr);
        k_act<<<(BSN * 64 + 255) / 256, 256, 0, stream>>>(t1, qf);
        k_lin4<1><<<dim3(12, 64), 256, 0, stream>>>(t1, wb + OB_W3, qf, pe, h, hb);
        k_linqkv<<<dim3(12, 64), 256, 0, stream>>>(hb, wb + OB_WQ, wb + OB_WK, wb + OB_WV, q, kk, vv);
        for (int l = 0; l < LLAY; ++l) {
            const unsigned short* wbo  = wb + OB_WO + (size_t)l * 28672;
            const unsigned short* wbf1 = wb + OB_F1 + (size_t)l * 114688;
            const unsigned short* wbf2 = wb + OB_F2 + (size_t)l * 114688;
            k_attn5<<<BB * HHEAD * 8, 256, 0, stream>>>(q, kk, vv, t1b);
            k_linwo<<<dim3(12, 64), 256, 0, stream>>>(t1b, wbo, h, hb);
            k_f1act<<<dim3(256, 4), 256, 0, stream>>>(hb, wbf1, qf, fmidb);
            if (l < LLAY - 1) {
                const unsigned short* wbq = wb + OB_WQ + (size_t)(l + 1) * 28672;
                const unsigned short* wbk = wb + OB_WK + (size_t)(l + 1) * 28672;
                const unsigned short* wbv = wb + OB_WV + (size_t)(l + 1) * 28672;
                k_f2qkv<1><<<dim3(12, 64), 256, 0, stream>>>(fmidb, wbf2, wbq, wbk, wbv, h, q, kk, vv);
            } else {
                k_f2qkv<0><<<dim3(12, 64), 256, 0, stream>>>(fmidb, wbf2, nullptr, nullptr, nullptr, h, nullptr, nullptr, nullptr);
            }
        }
    };

    k_init_qf<<<1, 256, 0, stream>>>(qf);
    k_init_pe<<<512, 64, 0, stream>>>(pe);
    run_half(x, efb, efw, ew1, ew2, ew3, ewq, ewk, ewv, ewo, ef1, ef2);
    k_fcvq<<<BSN, 256, 0, stream>>>(h, eow, qf, cb, z, zvq, zst);
    run_half(zst, dfb, dfw, dw1, dw2, dw3, dwq, dwk, dwv, dwo, df1, df2);
    k_fcout<<<BSN, 64, 0, stream>>>(h, dow, qf, z2);
    k_loss<<<96, 256, 0, stream>>>(x, z2, z, zvq, out, p1, p2);
    k_final<<<1, 64, 0, stream>>>(p1, p2, out);
}

// Round 13
// 930.952 us; speedup vs baseline: 1.0383x; 1.0383x over previous
//
#include <hip/hip_runtime.h>
#include <math.h>

#define BB 8
#define SS 512
#define HHEAD 8
#define LLAY 4
#define KCB 1024
#define BSN 4096          // B*S
#define ROWS 49152        // BS*12
#define NEL 49152         // B*S*12

__constant__ int d_REP[12] = {0,1,2,2,3,3,4,4,5,5,6,6};

typedef __attribute__((ext_vector_type(8))) short bf16x8;
typedef __attribute__((ext_vector_type(4))) float f32x4;

// bf16 weight-region offsets (ushorts) inside wb
#define OB_W2 0
#define OB_W3 28672
#define OB_WQ 57344        // + l*28672
#define OB_WK 172032
#define OB_WV 286720
#define OB_WO 401408
#define OB_F1 516096       // + l*114688
#define OB_F2 974848
#define WB_TOTAL 1433600

__device__ inline unsigned short f2bf(float x) {
    unsigned u = __builtin_bit_cast(unsigned, x);
    u += 0x7FFF + ((u >> 16) & 1);
    return (unsigned short)(u >> 16);
}

// fast gelu: erf via Abramowitz-Stegun 7.1.26 (|err| < 1.5e-7), HW rcp
__device__ inline float fast_gelu(float a) {
    float x = a * 0.7071067811865475f;
    float ax = fabsf(x);
    float tt = __builtin_amdgcn_rcpf(fmaf(0.3275911f, ax, 1.0f));
    float poly = ((((1.061405429f * tt - 1.453152027f) * tt + 1.421413741f) * tt
                   - 0.284496736f) * tt + 0.254829592f) * tt;
    float y = fmaf(-poly, __expf(-x * x), 1.0f);
    return 0.5f * a * (1.0f + copysignf(y, x));
}

// packed (float2) gelu — written to encourage v_pk_* emission
__device__ inline float2 fast_gelu2(float2 a) {
    float2 x  = make_float2(a.x * 0.7071067811865475f, a.y * 0.7071067811865475f);
    float2 tt = make_float2(
        __builtin_amdgcn_rcpf(fmaf(0.3275911f, fabsf(x.x), 1.0f)),
        __builtin_amdgcn_rcpf(fmaf(0.3275911f, fabsf(x.y), 1.0f)));
    float2 p = make_float2(fmaf(1.061405429f, tt.x, -1.453152027f),
                           fmaf(1.061405429f, tt.y, -1.453152027f));
    p = make_float2(fmaf(p.x, tt.x, 1.421413741f),  fmaf(p.y, tt.y, 1.421413741f));
    p = make_float2(fmaf(p.x, tt.x, -0.284496736f), fmaf(p.y, tt.y, -0.284496736f));
    p = make_float2(fmaf(p.x, tt.x, 0.254829592f),  fmaf(p.y, tt.y, 0.254829592f));
    p = make_float2(p.x * tt.x, p.y * tt.y);
    float2 ex = make_float2(__expf(-x.x * x.x), __expf(-x.y * x.y));
    float2 y  = make_float2(fmaf(-p.x, ex.x, 1.0f), fmaf(-p.y, ex.y, 1.0f));
    float2 er = make_float2(copysignf(y.x, x.x), copysignf(y.y, x.y));
    return make_float2(0.5f * a.x * (1.0f + er.x), 0.5f * a.y * (1.0f + er.y));
}

// symmetry-reduced act on one 12-vector (tables in qf[160..] / qf[256..])
__device__ inline void act12(const float* __restrict__ qf, const float v[12], float o[12]) {
    constexpr int S_[7]  = {0, 1, 2, 4, 6, 8, 10};
    constexpr int DKv[7] = {1, 1, 2, 2, 2, 2, 2};
    constexpr int P_[7]  = {1, 2, 12, 6, 4, 3, 12};
    constexpr int UO[7]  = {0, 1, 3, 15, 21, 25, 28};
    constexpr int OO[7]  = {0, 1, 3, 27, 39, 47, 53};
    const float* QP = qf + 160;
    const float* QO = qf + 256;
#pragma unroll
    for (int k = 0; k < 7; ++k) {
        float g[12];
#pragma unroll
        for (int u = 0; u < P_[k]; ++u) {
            float p = QP[(UO[k] + u) * 2] * v[S_[k]];
            if (DKv[k] == 2) p = fmaf(QP[(UO[k] + u) * 2 + 1], v[S_[k] + 1], p);
            g[u] = fast_gelu(p);
        }
#pragma unroll
        for (int d = 0; d < DKv[k]; ++d) {
            float a = 0.f;
#pragma unroll
            for (int u = 0; u < P_[k]; ++u) a = fmaf(QO[OO[k] + d * P_[k] + u], g[u], a);
            o[S_[k] + d] = a;
        }
    }
}

// packed act: two independent positions per call
__device__ inline void act12p(const float* __restrict__ qf, const float2 v[12], float2 o[12]) {
    constexpr int S_[7]  = {0, 1, 2, 4, 6, 8, 10};
    constexpr int DKv[7] = {1, 1, 2, 2, 2, 2, 2};
    constexpr int P_[7]  = {1, 2, 12, 6, 4, 3, 12};
    constexpr int UO[7]  = {0, 1, 3, 15, 21, 25, 28};
    constexpr int OO[7]  = {0, 1, 3, 27, 39, 47, 53};
    const float* QP = qf + 160;
    const float* QO = qf + 256;
#pragma unroll
    for (int k = 0; k < 7; ++k) {
        float2 g[12];
#pragma unroll
        for (int u = 0; u < P_[k]; ++u) {
            float c0 = QP[(UO[k] + u) * 2];
            float2 p = make_float2(c0 * v[S_[k]].x, c0 * v[S_[k]].y);
            if (DKv[k] == 2) {
                float c1 = QP[(UO[k] + u) * 2 + 1];
                p = make_float2(fmaf(c1, v[S_[k] + 1].x, p.x), fmaf(c1, v[S_[k] + 1].y, p.y));
            }
            g[u] = fast_gelu2(p);
        }
#pragma unroll
        for (int d = 0; d < DKv[k]; ++d) {
            float2 a = make_float2(0.f, 0.f);
#pragma unroll
            for (int u = 0; u < P_[k]; ++u) {
                float c = QO[OO[k] + d * P_[k] + u];
                a = make_float2(fmaf(c, g[u].x, a.x), fmaf(c, g[u].y, a.y));
            }
            o[S_[k] + d] = a;
        }
    }
}

// ---------------- QF init + rowsums + reduced act tables ----------------
__global__ void k_init_qf(float* qf) {
    int t = threadIdx.x;
    if (t < 144) {
        int r = t / 12, j = t % 12;
        double v;
        if (r == 0)      v = 1.0 / sqrt(12.0);
        else if (r == 1) v = ((j & 1) ? -1.0 : 1.0) / sqrt(12.0);
        else {
            int m = r >> 1;
            double ang = 2.0 * 3.14159265358979323846 * (double)m * (double)j / 12.0;
            v = (((r & 1) == 0) ? cos(ang) : sin(ang)) / sqrt(6.0);
        }
        qf[t] = (float)v;
    }
    __syncthreads();
    if (t < 12) {
        float s = 0.f;
        for (int j = 0; j < 12; ++j) s += qf[t * 12 + j];
        qf[144 + t] = s;
    }
    __syncthreads();
    if (t == 0) {
        const int S_[7]  = {0, 1, 2, 4, 6, 8, 10};
        const int DKv[7] = {1, 1, 2, 2, 2, 2, 2};
        const int P_[7]  = {1, 2, 12, 6, 4, 3, 12};
        const int UO[7]  = {0, 1, 3, 15, 21, 25, 28};
        const int OO[7]  = {0, 1, 3, 27, 39, 47, 53};
        for (int k = 0; k < 7; ++k) {
            for (int u = 0; u < P_[k]; ++u) {
                qf[160 + (UO[k] + u) * 2]     = qf[S_[k] * 12 + u];
                qf[160 + (UO[k] + u) * 2 + 1] = (DKv[k] == 2) ? qf[(S_[k] + 1) * 12 + u] : 0.f;
            }
            for (int d = 0; d < DKv[k]; ++d)
                for (int u = 0; u < P_[k]; ++u) {
                    float a = 0.f;
                    for (int pp = u; pp < 12; pp += P_[k]) a += qf[(S_[k] + d) * 12 + pp];
                    qf[256 + OO[k] + d * P_[k] + u] = a;
                }
        }
    }
}

// ---------------- pe table [512][64] ----------------
__global__ void k_init_pe(float* pe) {
    int s = blockIdx.x, m = threadIdx.x;
    int i = m >> 1;
    float dv = expf((float)(2 * i) * (-0.14391156831212787f));
    float arg = (float)s * dv;
    pe[s * 64 + m] = (m & 1) ? cosf(arg) : sinf(arg);
}

// ---------------- weight bf16 pre-conversion (one half) -----------------
__global__ __launch_bounds__(256) void k_cvtw(const float* __restrict__ w2,
                                              const float* __restrict__ w3,
                                              const float* __restrict__ wq,
                                              const float* __restrict__ wk,
                                              const float* __restrict__ wv,
                                              const float* __restrict__ wo,
                                              const float* __restrict__ f1,
                                              const float* __restrict__ f2,
                                              unsigned short* __restrict__ dst) {
    int i = blockIdx.x * 256 + threadIdx.x;   // float4 index
    const float* src; int off;
    if      (i <   7168) { src = w2; off = i; }
    else if (i <  14336) { src = w3; off = i -   7168; }
    else if (i <  43008) { src = wq; off = i -  14336; }
    else if (i <  71680) { src = wk; off = i -  43008; }
    else if (i < 100352) { src = wv; off = i -  71680; }
    else if (i < 129024) { src = wo; off = i - 100352; }
    else if (i < 243712) { src = f1; off = i - 129024; }
    else if (i < 358400) { src = f2; off = i - 243712; }
    else return;
    float4 v = ((const float4*)src)[off];
    ushort4 u = {f2bf(v.x), f2bf(v.y), f2bf(v.z), f2bf(v.w)};
    *(ushort4*)(dst + (size_t)i * 4) = u;
}

// ---------------- fused embed + act64: 4 bs per block -------------------
__global__ __launch_bounds__(256) void k_embact(const float* __restrict__ x,
                                                const float* __restrict__ fb,
                                                const float* __restrict__ fw,
                                                const float* __restrict__ w1,
                                                const float* __restrict__ qf,
                                                float* __restrict__ out) {
    int bs0 = blockIdx.x * 4;
    int t = threadIdx.x;
    __shared__ float xs[4][12], h1[4][12];
    if (t < 48) {
        int sb = t / 12, j = t % 12;
        xs[sb][j] = x[(bs0 + sb) * 12 + j] + fb[0];
    }
    __syncthreads();
    if (t < 48) {
        int sb = t / 12, j = t % 12;
        float a = 0.f;
        for (int p = 0; p < 12; ++p) a += qf[j * 12 + p] * xs[sb][p];
        h1[sb][j] = a * fw[0];
    }
    __syncthreads();
    int sb = t >> 6, m = t & 63;
    float v[12], o[12];
#pragma unroll
    for (int d = 0; d < 12; ++d) v[d] = h1[sb][d] * w1[d_REP[d] * 64 + m];
    act12(qf, v, o);
    float* ob = out + ((size_t)(bs0 + sb) * 12) * 64 + m;
#pragma unroll
    for (int d = 0; d < 12; ++d) ob[d * 64] = o[d];
}

// ---------------- act standalone (t1, paired cols, float2) --------------
__global__ __launch_bounds__(256) void k_act(float* __restrict__ h,
                                             const float* __restrict__ qf) {
    int idx = blockIdx.x * 256 + threadIdx.x;
    if (idx >= BSN * 32) return;
    int bs = idx >> 5, m2 = (idx & 31) * 2;
    float* base = h + (size_t)bs * 12 * 64 + m2;
    float2 v[12], o[12];
#pragma unroll
    for (int d = 0; d < 12; ++d) v[d] = *(const float2*)&base[d * 64];
    act12p(qf, v, o);
#pragma unroll
    for (int d = 0; d < 12; ++d) *(float2*)&base[d * 64] = o[d];
}

// ---------------- MFMA bf16 lin (A fp32, B bf16). PE also writes hb -----
template <int PE>
__global__ __launch_bounds__(256) void k_lin4(const float* __restrict__ in,
                                              const unsigned short* __restrict__ Wb,
                                              const float* __restrict__ qfp,
                                              const float* __restrict__ pe,
                                              float* __restrict__ outv,
                                              unsigned short* __restrict__ hb) {
    const int d   = blockIdx.x;
    const int bs0 = blockIdx.y * 64;
    __shared__ unsigned short sA[64 * 72];
    __shared__ unsigned short sB[64 * 72];
    const int t  = threadIdx.x;
    const int w  = t >> 6;
    const int l  = t & 63;
    const int lr = l & 15;
    const int lk = l >> 4;

    f32x4 acc[4];
#pragma unroll
    for (int f = 0; f < 4; ++f) acc[f] = (f32x4){0.f, 0.f, 0.f, 0.f};

    const unsigned short* wbase = Wb + (size_t)d_REP[d] * 64 * 64;

    for (int e = t; e < 1024; e += 256) {
        int r = e >> 4, qq = e & 15;
        float4 v = *(const float4*)(in + ((size_t)(bs0 + r) * 12 + d) * 64 + qq * 4);
        ushort4 u = {f2bf(v.x), f2bf(v.y), f2bf(v.z), f2bf(v.w)};
        *(ushort4*)&sA[r * 72 + qq * 4] = u;
    }
    for (int e = t; e < 512; e += 256) {
        int c = e >> 3, seg = e & 7;
        *(bf16x8*)&sB[c * 72 + seg * 8] = *(const bf16x8*)(wbase + c * 64 + seg * 8);
    }
    __syncthreads();
#pragma unroll
    for (int ks = 0; ks < 2; ++ks) {
        bf16x8 a = *(const bf16x8*)&sA[(w * 16 + lr) * 72 + ks * 32 + lk * 8];
#pragma unroll
        for (int f = 0; f < 4; ++f) {
            bf16x8 b = *(const bf16x8*)&sB[(f * 16 + lr) * 72 + ks * 32 + lk * 8];
            acc[f] = __builtin_amdgcn_mfma_f32_16x16x32_bf16(a, b, acc[f], 0, 0, 0);
        }
    }

#pragma unroll
    for (int f = 0; f < 4; ++f) {
#pragma unroll
        for (int reg = 0; reg < 4; ++reg) {
            int bs = bs0 + w * 16 + lk * 4 + reg;
            int o  = f * 16 + lr;
            float val = acc[f][reg];
            size_t row = (size_t)bs * 12 + d;
            if (PE) val += qfp[144 + d] * pe[(bs & 511) * 64 + o];
            outv[row * 64 + o] = val;
            if (PE) hb[row * 64 + o] = f2bf(val);
        }
    }
}

// ---------------- wo-GEMM: A bf16 (attn out), B bf16, h +=, hb out ------
__global__ __launch_bounds__(256) void k_linwo(const unsigned short* __restrict__ t1b,
                                               const unsigned short* __restrict__ Wb,
                                               float* __restrict__ h,
                                               unsigned short* __restrict__ hb) {
    const int d   = blockIdx.x;
    const int bs0 = blockIdx.y * 64;
    __shared__ unsigned short sA[64 * 72];
    __shared__ unsigned short sB[64 * 72];
    const int t  = threadIdx.x;
    const int w  = t >> 6;
    const int l  = t & 63;
    const int lr = l & 15;
    const int lk = l >> 4;

    f32x4 acc[4];
#pragma unroll
    for (int f = 0; f < 4; ++f) acc[f] = (f32x4){0.f, 0.f, 0.f, 0.f};

    const unsigned short* wbase = Wb + (size_t)d_REP[d] * 64 * 64;

    for (int e = t; e < 512; e += 256) {
        int r = e >> 3, seg = e & 7;
        *(bf16x8*)&sA[r * 72 + seg * 8] =
            *(const bf16x8*)(t1b + ((size_t)(bs0 + r) * 12 + d) * 64 + seg * 8);
    }
    for (int e = t; e < 512; e += 256) {
        int c = e >> 3, seg = e & 7;
        *(bf16x8*)&sB[c * 72 + seg * 8] = *(const bf16x8*)(wbase + c * 64 + seg * 8);
    }
    __syncthreads();
#pragma unroll
    for (int ks = 0; ks < 2; ++ks) {
        bf16x8 a = *(const bf16x8*)&sA[(w * 16 + lr) * 72 + ks * 32 + lk * 8];
#pragma unroll
        for (int f = 0; f < 4; ++f) {
            bf16x8 b = *(const bf16x8*)&sB[(f * 16 + lr) * 72 + ks * 32 + lk * 8];
            acc[f] = __builtin_amdgcn_mfma_f32_16x16x32_bf16(a, b, acc[f], 0, 0, 0);
        }
    }

#pragma unroll
    for (int f = 0; f < 4; ++f) {
#pragma unroll
        for (int reg = 0; reg < 4; ++reg) {
            int bs = bs0 + w * 16 + lk * 4 + reg;
            int o  = f * 16 + lr;
            size_t row = (size_t)bs * 12 + d;
            float val = acc[f][reg] + h[row * 64 + o];
            h[row * 64 + o] = val;
            hb[row * 64 + o] = f2bf(val);
        }
    }
}

// ---------------- QKV projection (A = hb bf16, B bf16) ------------------
__global__ __launch_bounds__(256) void k_linqkv(const unsigned short* __restrict__ hbin,
                                                const unsigned short* __restrict__ wq,
                                                const unsigned short* __restrict__ wk,
                                                const unsigned short* __restrict__ wv,
                                                unsigned short* __restrict__ oq,
                                                unsigned short* __restrict__ ok,
                                                unsigned short* __restrict__ ov) {
    const int d   = blockIdx.x;
    const int bs0 = blockIdx.y * 64;
    __shared__ unsigned short sA[64 * 72];
    __shared__ unsigned short sB[64 * 72];
    const int t  = threadIdx.x;
    const int w  = t >> 6;
    const int l  = t & 63;
    const int lr = l & 15;
    const int lk = l >> 4;
    const int rep = d_REP[d];

    for (int e = t; e < 512; e += 256) {
        int r = e >> 3, seg = e & 7;
        *(bf16x8*)&sA[r * 72 + seg * 8] =
            *(const bf16x8*)(hbin + ((size_t)(bs0 + r) * 12 + d) * 64 + seg * 8);
    }

    for (int part = 0; part < 3; ++part) {
        const unsigned short* wsel = (part == 0) ? wq : (part == 1) ? wk : wv;
        const unsigned short* wbase = wsel + (size_t)rep * 64 * 64;
        __syncthreads();
        for (int e = t; e < 512; e += 256) {
            int c = e >> 3, seg = e & 7;
            *(bf16x8*)&sB[c * 72 + seg * 8] = *(const bf16x8*)(wbase + c * 64 + seg * 8);
        }
        __syncthreads();
        f32x4 acc[4];
#pragma unroll
        for (int f = 0; f < 4; ++f) acc[f] = (f32x4){0.f, 0.f, 0.f, 0.f};
#pragma unroll
        for (int ks = 0; ks < 2; ++ks) {
            bf16x8 a = *(const bf16x8*)&sA[(w * 16 + lr) * 72 + ks * 32 + lk * 8];
#pragma unroll
            for (int f = 0; f < 4; ++f) {
                bf16x8 b = *(const bf16x8*)&sB[(f * 16 + lr) * 72 + ks * 32 + lk * 8];
                acc[f] = __builtin_amdgcn_mfma_f32_16x16x32_bf16(a, b, acc[f], 0, 0, 0);
            }
        }
        unsigned short* oh = (part == 0) ? oq : (part == 1) ? ok : ov;
#pragma unroll
        for (int f = 0; f < 4; ++f) {
#pragma unroll
            for (int reg = 0; reg < 4; ++reg) {
                int bs = bs0 + w * 16 + lk * 4 + reg;
                int o  = f * 16 + lr;
                int b = bs >> 9, s = bs & 511;
                unsigned short hv = f2bf(acc[f][reg]);
                if (part < 2)
                    oh[(((size_t)(b * 8 + (o >> 3)) * 512 + s) * 96) + d * 8 + (o & 7)] = hv;
                else
                    oh[(((size_t)(b * 8 + (o >> 3)) * 96 + d * 8 + (o & 7)) * 512) + s] = hv;
            }
        }
    }
}

// ---------------- attention v6: 128 q-rows, 8 waves, half staging -------
__global__ __launch_bounds__(512) void k_attn6(const unsigned short* __restrict__ qh,
                                               const unsigned short* __restrict__ kh,
                                               const unsigned short* __restrict__ vt,
                                               unsigned short* __restrict__ out) {
    __shared__ unsigned short sK[64 * 104];
    __shared__ unsigned short sV[96 * 72];
    __shared__ unsigned short ps[8][16 * 72];
    const int bh = blockIdx.x >> 2;
    const int q0 = (blockIdx.x & 3) * 128;
    const int t = threadIdx.x;
    const int w = t >> 6;
    const int l = t & 63;
    const int lr = l & 15;
    const int lk = l >> 4;

    const unsigned short* qg = qh + ((size_t)bh * 512 + q0 + w * 16) * 96;
    bf16x8 qa[3];
#pragma unroll
    for (int ks = 0; ks < 3; ++ks)
        qa[ks] = *(const bf16x8*)(qg + (size_t)lr * 96 + ks * 32 + lk * 8);

    float ts[4] = {0.f, 0.f, 0.f, 0.f};
    f32x4 o[6];
#pragma unroll
    for (int f = 0; f < 6; ++f) o[f] = (f32x4){0.f, 0.f, 0.f, 0.f};

    const unsigned short* kg = kh + (size_t)bh * 512 * 96;
    const unsigned short* vg = vt + (size_t)bh * 96 * 512;
    const float scale = 0.10206207261596577f;   // 1/sqrt(96)

    for (int tile = 0; tile < 8; ++tile) {
        __syncthreads();
        for (int e = t; e < 768; e += 512) {
            int row = e / 12, seg = e % 12;
            *(bf16x8*)&sK[row * 104 + seg * 8] =
                *(const bf16x8*)(kg + ((size_t)(tile * 64 + row)) * 96 + seg * 8);
        }
        for (int e = t; e < 768; e += 512) {
            int row = e / 8, seg = e % 8;
            *(bf16x8*)&sV[row * 72 + seg * 8] =
                *(const bf16x8*)(vg + (size_t)row * 512 + tile * 64 + seg * 8);
        }
        __syncthreads();

#pragma unroll
        for (int f = 0; f < 4; ++f) {
            f32x4 acc = {0.f, 0.f, 0.f, 0.f};
#pragma unroll
            for (int ks = 0; ks < 3; ++ks) {
                bf16x8 kb = *(const bf16x8*)&sK[(f * 16 + lr) * 104 + ks * 32 + lk * 8];
                acc = __builtin_amdgcn_mfma_f32_16x16x32_bf16(qa[ks], kb, acc, 0, 0, 0);
            }
#pragma unroll
            for (int r = 0; r < 4; ++r) {
                float p = __expf(acc[r] * scale);
                ts[r] += p;
                ps[w][(lk * 4 + r) * 72 + f * 16 + lr] = f2bf(p);
            }
        }

        bf16x8 pa[2];
#pragma unroll
        for (int ks = 0; ks < 2; ++ks)
            pa[ks] = *(const bf16x8*)&ps[w][lr * 72 + ks * 32 + lk * 8];
#pragma unroll
        for (int f = 0; f < 6; ++f) {
            f32x4 acc = o[f];
#pragma unroll
            for (int ks = 0; ks < 2; ++ks) {
                bf16x8 vb = *(const bf16x8*)&sV[(f * 16 + lr) * 72 + ks * 32 + lk * 8];
                acc = __builtin_amdgcn_mfma_f32_16x16x32_bf16(pa[ks], vb, acc, 0, 0, 0);
            }
            o[f] = acc;
        }
    }

    float inv[4];
#pragma unroll
    for (int r = 0; r < 4; ++r) {
        float s2 = ts[r];
#pragma unroll
        for (int d = 1; d < 16; d <<= 1) s2 += __shfl_xor(s2, d);
        inv[r] = 1.0f / s2;
    }
    const int b = bh >> 3, hh = bh & 7;
#pragma unroll
    for (int r = 0; r < 4; ++r) {
        int s = q0 + w * 16 + lk * 4 + r;
        unsigned short* ob = out + ((size_t)(b * 512 + s) * 12) * 64 + hh * 8;
#pragma unroll
        for (int f = 0; f < 6; ++f) {
            int col = f * 16 + lr;
            ob[(col >> 3) * 64 + (col & 7)] = f2bf(o[f][r] * inv[r]);
        }
    }
}

// ---------------- fused f1-GEMM + act (packed) -> bf16 fmid -------------
__global__ __launch_bounds__(256, 4) void k_f1act(const unsigned short* __restrict__ hb,
                                                  const unsigned short* __restrict__ f1wb,
                                                  const float* __restrict__ qf,
                                                  unsigned short* __restrict__ fmidb) {
    constexpr int S_[7]  = {0, 1, 2, 4, 6, 8, 10};
    constexpr int DKv[7] = {1, 1, 2, 2, 2, 2, 2};
    const int bs0 = blockIdx.x * 16;
    const int c0  = blockIdx.y * 64;
    __shared__ unsigned short sB[64 * 72];
    const int t  = threadIdx.x;
    const int w  = t >> 6;      // wave = col fragment
    const int l  = t & 63;
    const int lr = l & 15;
    const int lk = l >> 4;

    f32x4 acc[12];
#pragma unroll
    for (int d = 0; d < 12; ++d) acc[d] = (f32x4){0.f, 0.f, 0.f, 0.f};

    const unsigned short* arow = hb + (size_t)(bs0 + lr) * 12 * 64 + lk * 8;

#pragma unroll
    for (int k = 0; k < 7; ++k) {
        if (k) __syncthreads();
        const unsigned short* wbase = f1wb + ((size_t)k * 256 + c0) * 64;
        for (int e = t; e < 512; e += 256) {
            int c = e >> 3, seg = e & 7;
            *(bf16x8*)&sB[c * 72 + seg * 8] = *(const bf16x8*)(wbase + c * 64 + seg * 8);
        }
        __syncthreads();
#pragma unroll
        for (int dd = 0; dd < 2; ++dd) {
            if (dd < DKv[k]) {
                int d = S_[k] + dd;
#pragma unroll
                for (int ks = 0; ks < 2; ++ks) {
                    bf16x8 a = *(const bf16x8*)(arow + (size_t)d * 64 + ks * 32);
                    bf16x8 b = *(const bf16x8*)&sB[(w * 16 + lr) * 72 + ks * 32 + lk * 8];
                    acc[d] = __builtin_amdgcn_mfma_f32_16x16x32_bf16(a, b, acc[d], 0, 0, 0);
                }
            }
        }
    }

    // packed act in registers + bf16 store (no barriers in this phase)
    int col = c0 + w * 16 + lr;
#pragma unroll
    for (int pp = 0; pp < 2; ++pp) {
        float2 v[12], o[12];
#pragma unroll
        for (int d = 0; d < 12; ++d) v[d] = make_float2(acc[d][pp * 2], acc[d][pp * 2 + 1]);
        act12p(qf, v, o);
        int row = bs0 + lk * 4 + pp * 2;
#pragma unroll
        for (int d = 0; d < 12; ++d) {
            fmidb[((size_t)row * 12 + d) * 256 + col]       = f2bf(o[d].x);
            fmidb[((size_t)(row + 1) * 12 + d) * 256 + col] = f2bf(o[d].y);
        }
    }
}

// ---------------- fused f2-GEMM (+res, h out) + next-layer QKV ----------
template <int QKV>
__global__ __launch_bounds__(256) void k_f2qkv(const unsigned short* __restrict__ inb,
                                               const unsigned short* __restrict__ Wf2,
                                               const unsigned short* __restrict__ wq,
                                               const unsigned short* __restrict__ wk,
                                               const unsigned short* __restrict__ wv,
                                               float* __restrict__ h,
                                               unsigned short* __restrict__ oq,
                                               unsigned short* __restrict__ ok,
                                               unsigned short* __restrict__ ov) {
    const int d   = blockIdx.x;
    const int bs0 = blockIdx.y * 64;
    __shared__ unsigned short sA[64 * 72];
    __shared__ unsigned short sB[64 * 72];
    __shared__ unsigned short sH[64 * 72];
    const int t  = threadIdx.x;
    const int w  = t >> 6;
    const int l  = t & 63;
    const int lr = l & 15;
    const int lk = l >> 4;
    const int rep = d_REP[d];

    f32x4 acc[4];
#pragma unroll
    for (int f = 0; f < 4; ++f) acc[f] = (f32x4){0.f, 0.f, 0.f, 0.f};

    const unsigned short* wbase = Wf2 + (size_t)rep * 64 * 256;

    // phase 1: h' = fmid * f2 + h
    for (int kc = 0; kc < 256; kc += 64) {
        __syncthreads();
        for (int e = t; e < 512; e += 256) {
            int r = e >> 3, seg = e & 7;
            *(bf16x8*)&sA[r * 72 + seg * 8] =
                *(const bf16x8*)(inb + ((size_t)(bs0 + r) * 12 + d) * 256 + kc + seg * 8);
        }
        for (int e = t; e < 512; e += 256) {
            int c = e >> 3, seg = e & 7;
            *(bf16x8*)&sB[c * 72 + seg * 8] =
                *(const bf16x8*)(wbase + (size_t)c * 256 + kc + seg * 8);
        }
        __syncthreads();
#pragma unroll
        for (int ks = 0; ks < 2; ++ks) {
            bf16x8 a = *(const bf16x8*)&sA[(w * 16 + lr) * 72 + ks * 32 + lk * 8];
#pragma unroll
            for (int f = 0; f < 4; ++f) {
                bf16x8 b = *(const bf16x8*)&sB[(f * 16 + lr) * 72 + ks * 32 + lk * 8];
                acc[f] = __builtin_amdgcn_mfma_f32_16x16x32_bf16(a, b, acc[f], 0, 0, 0);
            }
        }
    }

#pragma unroll
    for (int f = 0; f < 4; ++f) {
#pragma unroll
        for (int reg = 0; reg < 4; ++reg) {
            int rloc = w * 16 + lk * 4 + reg;
            int bs = bs0 + rloc;
            int o  = f * 16 + lr;
            size_t row = (size_t)bs * 12 + d;
            float val = acc[f][reg] + h[row * 64 + o];
            h[row * 64 + o] = val;
            if (QKV) sH[rloc * 72 + o] = f2bf(val);
        }
    }

    // phase 2: QKV for the next layer from sH
    if (QKV) {
        for (int part = 0; part < 3; ++part) {
            const unsigned short* wsel = (part == 0) ? wq : (part == 1) ? wk : wv;
            const unsigned short* wb2 = wsel + (size_t)rep * 64 * 64;
            __syncthreads();
            for (int e = t; e < 512; e += 256) {
                int c = e >> 3, seg = e & 7;
                *(bf16x8*)&sB[c * 72 + seg * 8] = *(const bf16x8*)(wb2 + c * 64 + seg * 8);
            }
            __syncthreads();
            f32x4 a2[4];
#pragma unroll
            for (int f = 0; f < 4; ++f) a2[f] = (f32x4){0.f, 0.f, 0.f, 0.f};
#pragma unroll
            for (int ks = 0; ks < 2; ++ks) {
                bf16x8 a = *(const bf16x8*)&sH[(w * 16 + lr) * 72 + ks * 32 + lk * 8];
#pragma unroll
                for (int f = 0; f < 4; ++f) {
                    bf16x8 b = *(const bf16x8*)&sB[(f * 16 + lr) * 72 + ks * 32 + lk * 8];
                    a2[f] = __builtin_amdgcn_mfma_f32_16x16x32_bf16(a, b, a2[f], 0, 0, 0);
                }
            }
            unsigned short* oh = (part == 0) ? oq : (part == 1) ? ok : ov;
#pragma unroll
            for (int f = 0; f < 4; ++f) {
#pragma unroll
                for (int reg = 0; reg < 4; ++reg) {
                    int bs = bs0 + w * 16 + lk * 4 + reg;
                    int o  = f * 16 + lr;
                    int b = bs >> 9, s = bs & 511;
                    unsigned short hv = f2bf(a2[f][reg]);
                    if (part < 2)
                        oh[(((size_t)(b * 8 + (o >> 3)) * 512 + s) * 96) + d * 8 + (o & 7)] = hv;
                    else
                        oh[(((size_t)(b * 8 + (o >> 3)) * 96 + d * 8 + (o & 7)) * 512) + s] = hv;
                }
            }
        }
    }
}

// ---------------- fc_out (decoder tail) ----------------
__global__ void k_fcout(const float* __restrict__ h, const float* __restrict__ w,
                        const float* __restrict__ qf, float* __restrict__ z) {
    int bs = blockIdx.x;
    __shared__ float td[12];
    int t = threadIdx.x;
    if (t < 12) {
        const float* row = h + ((size_t)bs * 12 + t) * 64;
        const float* wr  = w + d_REP[t] * 64;
        float a = 0.f;
        for (int i = 0; i < 64; ++i) a += row[i] * wr[i];
        td[t] = a;
    }
    __syncthreads();
    if (t < 12) {
        float a = 0.f;
        for (int d = 0; d < 12; ++d) a += qf[d * 12 + t] * td[d];
        z[bs * 12 + t] = a / 7.0f;
    }
}

// ---------------- fused fc_out + VQ (encoder tail) ----------------------
__global__ __launch_bounds__(256) void k_fcvq(const float* __restrict__ h,
                                              const float* __restrict__ w,
                                              const float* __restrict__ qf,
                                              const float* __restrict__ cb,
                                              float* __restrict__ z,
                                              float* __restrict__ zvq,
                                              float* __restrict__ zst) {
    int bs = blockIdx.x;
    int t = threadIdx.x;
    __shared__ float td[12];
    __shared__ float zv[12];
    __shared__ float sb[256];
    __shared__ int   si[256];
    if (t < 12) {
        const float* row = h + ((size_t)bs * 12 + t) * 64;
        const float* wr  = w + d_REP[t] * 64;
        float a = 0.f;
        for (int i = 0; i < 64; ++i) a += row[i] * wr[i];
        td[t] = a;
    }
    __syncthreads();
    if (t < 12) {
        float a = 0.f;
        for (int d = 0; d < 12; ++d) a += qf[d * 12 + t] * td[d];
        a /= 7.0f;
        zv[t] = a;
        z[bs * 12 + t] = a;
    }
    __syncthreads();
    float zz = 0.f;
    for (int j = 0; j < 12; ++j) zz += zv[j] * zv[j];
    float best = 3.4e38f; int bi = 0x7fffffff;
    for (int c = t; c < KCB; c += 256) {
        const float* cr = cb + c * 12;
        float cc = 0.f, dot = 0.f;
        for (int j = 0; j < 12; ++j) { cc += cr[j] * cr[j]; dot += zv[j] * cr[j]; }
        float dist = zz + cc - 2.0f * dot;
        if (dist < best) { best = dist; bi = c; }
    }
    sb[t] = best; si[t] = bi; __syncthreads();
    for (int st = 128; st > 0; st >>= 1) {
        if (t < st) {
            if (sb[t + st] < sb[t] || (sb[t + st] == sb[t] && si[t + st] < si[t])) {
                sb[t] = sb[t + st]; si[t] = si[t + st];
            }
        }
        __syncthreads();
    }
    if (t < 12) {
        float c = cb[si[0] * 12 + t];
        zvq[bs * 12 + t] = c;
        float zi = zv[t];
        zst[bs * 12 + t] = (c - zi) + zi;
    }
}

// ---------------- merged losses ----------------
__global__ __launch_bounds__(256) void k_loss(const float* __restrict__ x,
                                              const float* __restrict__ logits,
                                              const float* __restrict__ z,
                                              const float* __restrict__ zvq,
                                              float* __restrict__ xr_out,
                                              float* __restrict__ p1,
                                              float* __restrict__ p2) {
    __shared__ float red[256];
    int t = threadIdx.x;
    float acc1 = 0.f, acc2 = 0.f;
    for (int i = blockIdx.x * 256 + t; i < NEL; i += gridDim.x * 256) {
        float lg = logits[i];
        float xr = 1.0f / (1.0f + expf(-lg));
        xr_out[i] = xr;
        float xi = x[i];
        float l1 = fmaxf(logf(xr), -100.0f);
        float l2 = fmaxf(logf(1.0f - xr), -100.0f);
        acc1 += xi * l1 + (1.0f - xi) * l2;
        float dd = zvq[i] - z[i];
        acc2 += dd * dd;
    }
    red[t] = acc1; __syncthreads();
    for (int st = 128; st > 0; st >>= 1) { if (t < st) red[t] += red[t + st]; __syncthreads(); }
    if (t == 0) p1[blockIdx.x] = red[0];
    __syncthreads();
    red[t] = acc2; __syncthreads();
    for (int st = 128; st > 0; st >>= 1) { if (t < st) red[t] += red[t + st]; __syncthreads(); }
    if (t == 0) p2[blockIdx.x] = red[0];
}

__global__ void k_final(const float* __restrict__ p1, const float* __restrict__ p2,
                        float* __restrict__ out) {
    if (threadIdx.x == 0) {
        float s1 = 0.f, s2 = 0.f;
        for (int i = 0; i < 96; ++i) { s1 += p1[i]; s2 += p2[i]; }
        out[NEL]     = -s1 / (float)NEL;
        out[NEL + 1] =  s2 / (float)NEL;
        out[NEL + 2] =  s2 / (float)NEL;
    }
}

// ------------------------------------------------------------------------
extern "C" void kernel_launch(void* const* d_in, const int* in_sizes, int n_in,
                              void* d_out, int out_size, void* d_ws, size_t ws_size,
                              hipStream_t stream) {
    const float* x   = (const float*)d_in[0];
    const float* efb = (const float*)d_in[1];
    const float* efw = (const float*)d_in[2];
    const float* ew1 = (const float*)d_in[3];
    const float* ew2 = (const float*)d_in[4];
    const float* ew3 = (const float*)d_in[5];
    const float* ewq = (const float*)d_in[6];
    const float* ewk = (const float*)d_in[7];
    const float* ewv = (const float*)d_in[8];
    const float* ewo = (const float*)d_in[9];
    const float* ef1 = (const float*)d_in[10];
    const float* ef2 = (const float*)d_in[11];
    const float* eow = (const float*)d_in[12];
    const float* cb  = (const float*)d_in[13];
    const float* dfb = (const float*)d_in[14];
    const float* dfw = (const float*)d_in[15];
    const float* dw1 = (const float*)d_in[16];
    const float* dw2 = (const float*)d_in[17];
    const float* dw3 = (const float*)d_in[18];
    const float* dwq = (const float*)d_in[19];
    const float* dwk = (const float*)d_in[20];
    const float* dwv = (const float*)d_in[21];
    const float* dwo = (const float*)d_in[22];
    const float* df1 = (const float*)d_in[23];
    const float* df2 = (const float*)d_in[24];
    const float* dow = (const float*)d_in[25];
    float* out = (float*)d_out;

    float* ws = (float*)d_ws;
    float* qf   = ws;                           // 512
    float* h    = ws + 512;                     // 3,145,728
    float* fmid = h + 3145728;                  // 12,582,912 region (bf16 fmid + q/kk/vv aliases)
    float* t1   = fmid + 12582912;              // 3,145,728 (fp32 head tmp; bf16 attn-out alias)
    float* z    = t1 + 3145728;
    float* zvq  = z + NEL;
    float* zst  = zvq + NEL;
    float* z2   = zst + NEL;
    float* p1   = z2 + NEL;
    float* p2   = p1 + 128;
    float* pe   = p2 + 128;                     // 32768
    unsigned short* wb = (unsigned short*)(pe + 32768);               // 1,433,600 ushorts
    unsigned short* hb = wb + WB_TOTAL;                               // 3,145,728 ushorts
    unsigned short* fmidb = (unsigned short*)fmid;                    // 12.6M ushorts
    unsigned short* q  = (unsigned short*)(fmid + 6291456);           // after fmidb
    unsigned short* kk = q + 3145728;
    unsigned short* vv = kk + 3145728;
    unsigned short* t1b = (unsigned short*)t1;

    auto run_half = [&](const float* xin, const float* fb, const float* fw,
                        const float* w1, const float* w2, const float* w3,
                        const float* wq, const float* wk, const float* wv,
                        const float* wo, const float* f1, const float* f2) {
        k_cvtw<<<1400, 256, 0, stream>>>(w2, w3, wq, wk, wv, wo, f1, f2, wb);
        k_embact<<<BSN / 4, 256, 0, stream>>>(xin, fb, fw, w1, qf, h);
        k_lin4<0><<<dim3(12, 64), 256, 0, stream>>>(h, wb + OB_W2, qf, nullptr, t1, nullptr);
        k_act<<<(BSN * 32 + 255) / 256, 256, 0, stream>>>(t1, qf);
        k_lin4<1><<<dim3(12, 64), 256, 0, stream>>>(t1, wb + OB_W3, qf, pe, h, hb);
        k_linqkv<<<dim3(12, 64), 256, 0, stream>>>(hb, wb + OB_WQ, wb + OB_WK, wb + OB_WV, q, kk, vv);
        for (int l = 0; l < LLAY; ++l) {
            const unsigned short* wbo  = wb + OB_WO + (size_t)l * 28672;
            const unsigned short* wbf1 = wb + OB_F1 + (size_t)l * 114688;
            const unsigned short* wbf2 = wb + OB_F2 + (size_t)l * 114688;
            k_attn6<<<BB * HHEAD * 4, 512, 0, stream>>>(q, kk, vv, t1b);
            k_linwo<<<dim3(12, 64), 256, 0, stream>>>(t1b, wbo, h, hb);
            k_f1act<<<dim3(256, 4), 256, 0, stream>>>(hb, wbf1, qf, fmidb);
            if (l < LLAY - 1) {
                const unsigned short* wbq = wb + OB_WQ + (size_t)(l + 1) * 28672;
                const unsigned short* wbk = wb + OB_WK + (size_t)(l + 1) * 28672;
                const unsigned short* wbv = wb + OB_WV + (size_t)(l + 1) * 28672;
                k_f2qkv<1><<<dim3(12, 64), 256, 0, stream>>>(fmidb, wbf2, wbq, wbk, wbv, h, q, kk, vv);
            } else {
                k_f2qkv<0><<<dim3(12, 64), 256, 0, stream>>>(fmidb, wbf2, nullptr, nullptr, nullptr, h, nullptr, nullptr, nullptr);
            }
        }
    };

    k_init_qf<<<1, 256, 0, stream>>>(qf);
    k_init_pe<<<512, 64, 0, stream>>>(pe);
    run_half(x, efb, efw, ew1, ew2, ew3, ewq, ewk, ewv, ewo, ef1, ef2);
    k_fcvq<<<BSN, 256, 0, stream>>>(h, eow, qf, cb, z, zvq, zst);
    run_half(zst, dfb, dfw, dw1, dw2, dw3, dwq, dwk, dwv, dwo, df1, df2);
    k_fcout<<<BSN, 64, 0, stream>>>(h, dow, qf, z2);
    k_loss<<<96, 256, 0, stream>>>(x, z2, z, zvq, out, p1, p2);
    k_final<<<1, 64, 0, stream>>>(p1, p2, out);
}

// Round 14
// 907.026 us; speedup vs baseline: 1.0657x; 1.0264x over previous
//
#include <hip/hip_runtime.h>
#include <math.h>

#define BB 8
#define SS 512
#define HHEAD 8
#define LLAY 4
#define KCB 1024
#define BSN 4096          // B*S
#define ROWS 49152        // BS*12
#define NEL 49152         // B*S*12

__constant__ int d_REP[12] = {0,1,2,2,3,3,4,4,5,5,6,6};

typedef __attribute__((ext_vector_type(8))) short bf16x8;
typedef __attribute__((ext_vector_type(4))) float f32x4;

// bf16 weight-region offsets (ushorts) inside wb
#define OB_W2 0
#define OB_W3 28672
#define OB_WQ 57344        // + l*28672
#define OB_WK 172032
#define OB_WV 286720
#define OB_WO 401408
#define OB_F1 516096       // + l*114688
#define OB_F2 974848
#define WB_TOTAL 1433600

__device__ inline unsigned short f2bf(float x) {
    unsigned u = __builtin_bit_cast(unsigned, x);
    u += 0x7FFF + ((u >> 16) & 1);
    return (unsigned short)(u >> 16);
}

// fast gelu: erf via Abramowitz-Stegun 7.1.26 (|err| < 1.5e-7), HW rcp
__device__ inline float fast_gelu(float a) {
    float x = a * 0.7071067811865475f;
    float ax = fabsf(x);
    float tt = __builtin_amdgcn_rcpf(fmaf(0.3275911f, ax, 1.0f));
    float poly = ((((1.061405429f * tt - 1.453152027f) * tt + 1.421413741f) * tt
                   - 0.284496736f) * tt + 0.254829592f) * tt;
    float y = fmaf(-poly, __expf(-x * x), 1.0f);
    return 0.5f * a * (1.0f + copysignf(y, x));
}

// packed (float2) gelu
__device__ inline float2 fast_gelu2(float2 a) {
    float2 x  = make_float2(a.x * 0.7071067811865475f, a.y * 0.7071067811865475f);
    float2 tt = make_float2(
        __builtin_amdgcn_rcpf(fmaf(0.3275911f, fabsf(x.x), 1.0f)),
        __builtin_amdgcn_rcpf(fmaf(0.3275911f, fabsf(x.y), 1.0f)));
    float2 p = make_float2(fmaf(1.061405429f, tt.x, -1.453152027f),
                           fmaf(1.061405429f, tt.y, -1.453152027f));
    p = make_float2(fmaf(p.x, tt.x, 1.421413741f),  fmaf(p.y, tt.y, 1.421413741f));
    p = make_float2(fmaf(p.x, tt.x, -0.284496736f), fmaf(p.y, tt.y, -0.284496736f));
    p = make_float2(fmaf(p.x, tt.x, 0.254829592f),  fmaf(p.y, tt.y, 0.254829592f));
    p = make_float2(p.x * tt.x, p.y * tt.y);
    float2 ex = make_float2(__expf(-x.x * x.x), __expf(-x.y * x.y));
    float2 y  = make_float2(fmaf(-p.x, ex.x, 1.0f), fmaf(-p.y, ex.y, 1.0f));
    float2 er = make_float2(copysignf(y.x, x.x), copysignf(y.y, x.y));
    return make_float2(0.5f * a.x * (1.0f + er.x), 0.5f * a.y * (1.0f + er.y));
}

// symmetry-reduced act on one 12-vector (tables in qf[160..] / qf[256..])
__device__ inline void act12(const float* __restrict__ qf, const float v[12], float o[12]) {
    constexpr int S_[7]  = {0, 1, 2, 4, 6, 8, 10};
    constexpr int DKv[7] = {1, 1, 2, 2, 2, 2, 2};
    constexpr int P_[7]  = {1, 2, 12, 6, 4, 3, 12};
    constexpr int UO[7]  = {0, 1, 3, 15, 21, 25, 28};
    constexpr int OO[7]  = {0, 1, 3, 27, 39, 47, 53};
    const float* QP = qf + 160;
    const float* QO = qf + 256;
#pragma unroll
    for (int k = 0; k < 7; ++k) {
        float g[12];
#pragma unroll
        for (int u = 0; u < P_[k]; ++u) {
            float p = QP[(UO[k] + u) * 2] * v[S_[k]];
            if (DKv[k] == 2) p = fmaf(QP[(UO[k] + u) * 2 + 1], v[S_[k] + 1], p);
            g[u] = fast_gelu(p);
        }
#pragma unroll
        for (int d = 0; d < DKv[k]; ++d) {
            float a = 0.f;
#pragma unroll
            for (int u = 0; u < P_[k]; ++u) a = fmaf(QO[OO[k] + d * P_[k] + u], g[u], a);
            o[S_[k] + d] = a;
        }
    }
}

// packed act: two independent positions per call
__device__ inline void act12p(const float* __restrict__ qf, const float2 v[12], float2 o[12]) {
    constexpr int S_[7]  = {0, 1, 2, 4, 6, 8, 10};
    constexpr int DKv[7] = {1, 1, 2, 2, 2, 2, 2};
    constexpr int P_[7]  = {1, 2, 12, 6, 4, 3, 12};
    constexpr int UO[7]  = {0, 1, 3, 15, 21, 25, 28};
    constexpr int OO[7]  = {0, 1, 3, 27, 39, 47, 53};
    const float* QP = qf + 160;
    const float* QO = qf + 256;
#pragma unroll
    for (int k = 0; k < 7; ++k) {
        float2 g[12];
#pragma unroll
        for (int u = 0; u < P_[k]; ++u) {
            float c0 = QP[(UO[k] + u) * 2];
            float2 p = make_float2(c0 * v[S_[k]].x, c0 * v[S_[k]].y);
            if (DKv[k] == 2) {
                float c1 = QP[(UO[k] + u) * 2 + 1];
                p = make_float2(fmaf(c1, v[S_[k] + 1].x, p.x), fmaf(c1, v[S_[k] + 1].y, p.y));
            }
            g[u] = fast_gelu2(p);
        }
#pragma unroll
        for (int d = 0; d < DKv[k]; ++d) {
            float2 a = make_float2(0.f, 0.f);
#pragma unroll
            for (int u = 0; u < P_[k]; ++u) {
                float c = QO[OO[k] + d * P_[k] + u];
                a = make_float2(fmaf(c, g[u].x, a.x), fmaf(c, g[u].y, a.y));
            }
            o[S_[k] + d] = a;
        }
    }
}

// ---------------- QF init + rowsums + reduced act tables ----------------
__global__ void k_init_qf(float* qf) {
    int t = threadIdx.x;
    if (t < 144) {
        int r = t / 12, j = t % 12;
        double v;
        if (r == 0)      v = 1.0 / sqrt(12.0);
        else if (r == 1) v = ((j & 1) ? -1.0 : 1.0) / sqrt(12.0);
        else {
            int m = r >> 1;
            double ang = 2.0 * 3.14159265358979323846 * (double)m * (double)j / 12.0;
            v = (((r & 1) == 0) ? cos(ang) : sin(ang)) / sqrt(6.0);
        }
        qf[t] = (float)v;
    }
    __syncthreads();
    if (t < 12) {
        float s = 0.f;
        for (int j = 0; j < 12; ++j) s += qf[t * 12 + j];
        qf[144 + t] = s;
    }
    __syncthreads();
    if (t == 0) {
        const int S_[7]  = {0, 1, 2, 4, 6, 8, 10};
        const int DKv[7] = {1, 1, 2, 2, 2, 2, 2};
        const int P_[7]  = {1, 2, 12, 6, 4, 3, 12};
        const int UO[7]  = {0, 1, 3, 15, 21, 25, 28};
        const int OO[7]  = {0, 1, 3, 27, 39, 47, 53};
        for (int k = 0; k < 7; ++k) {
            for (int u = 0; u < P_[k]; ++u) {
                qf[160 + (UO[k] + u) * 2]     = qf[S_[k] * 12 + u];
                qf[160 + (UO[k] + u) * 2 + 1] = (DKv[k] == 2) ? qf[(S_[k] + 1) * 12 + u] : 0.f;
            }
            for (int d = 0; d < DKv[k]; ++d)
                for (int u = 0; u < P_[k]; ++u) {
                    float a = 0.f;
                    for (int pp = u; pp < 12; pp += P_[k]) a += qf[(S_[k] + d) * 12 + pp];
                    qf[256 + OO[k] + d * P_[k] + u] = a;
                }
        }
    }
}

// ---------------- pe table [512][64] ----------------
__global__ void k_init_pe(float* pe) {
    int s = blockIdx.x, m = threadIdx.x;
    int i = m >> 1;
    float dv = expf((float)(2 * i) * (-0.14391156831212787f));
    float arg = (float)s * dv;
    pe[s * 64 + m] = (m & 1) ? cosf(arg) : sinf(arg);
}

// ---------------- weight bf16 pre-conversion (one half) -----------------
__global__ __launch_bounds__(256) void k_cvtw(const float* __restrict__ w2,
                                              const float* __restrict__ w3,
                                              const float* __restrict__ wq,
                                              const float* __restrict__ wk,
                                              const float* __restrict__ wv,
                                              const float* __restrict__ wo,
                                              const float* __restrict__ f1,
                                              const float* __restrict__ f2,
                                              unsigned short* __restrict__ dst) {
    int i = blockIdx.x * 256 + threadIdx.x;   // float4 index
    const float* src; int off;
    if      (i <   7168) { src = w2; off = i; }
    else if (i <  14336) { src = w3; off = i -   7168; }
    else if (i <  43008) { src = wq; off = i -  14336; }
    else if (i <  71680) { src = wk; off = i -  43008; }
    else if (i < 100352) { src = wv; off = i -  71680; }
    else if (i < 129024) { src = wo; off = i - 100352; }
    else if (i < 243712) { src = f1; off = i - 129024; }
    else if (i < 358400) { src = f2; off = i - 243712; }
    else return;
    float4 v = ((const float4*)src)[off];
    ushort4 u = {f2bf(v.x), f2bf(v.y), f2bf(v.z), f2bf(v.w)};
    *(ushort4*)(dst + (size_t)i * 4) = u;
}

// ---------------- fused embed + act64: 4 bs per block -------------------
__global__ __launch_bounds__(256) void k_embact(const float* __restrict__ x,
                                                const float* __restrict__ fb,
                                                const float* __restrict__ fw,
                                                const float* __restrict__ w1,
                                                const float* __restrict__ qf,
                                                float* __restrict__ out) {
    int bs0 = blockIdx.x * 4;
    int t = threadIdx.x;
    __shared__ float xs[4][12], h1[4][12];
    if (t < 48) {
        int sb = t / 12, j = t % 12;
        xs[sb][j] = x[(bs0 + sb) * 12 + j] + fb[0];
    }
    __syncthreads();
    if (t < 48) {
        int sb = t / 12, j = t % 12;
        float a = 0.f;
        for (int p = 0; p < 12; ++p) a += qf[j * 12 + p] * xs[sb][p];
        h1[sb][j] = a * fw[0];
    }
    __syncthreads();
    int sb = t >> 6, m = t & 63;
    float v[12], o[12];
#pragma unroll
    for (int d = 0; d < 12; ++d) v[d] = h1[sb][d] * w1[d_REP[d] * 64 + m];
    act12(qf, v, o);
    float* ob = out + ((size_t)(bs0 + sb) * 12) * 64 + m;
#pragma unroll
    for (int d = 0; d < 12; ++d) ob[d * 64] = o[d];
}

// ---------------- act standalone (t1, paired cols, float2) --------------
__global__ __launch_bounds__(256) void k_act(float* __restrict__ h,
                                             const float* __restrict__ qf) {
    int idx = blockIdx.x * 256 + threadIdx.x;
    if (idx >= BSN * 32) return;
    int bs = idx >> 5, m2 = (idx & 31) * 2;
    float* base = h + (size_t)bs * 12 * 64 + m2;
    float2 v[12], o[12];
#pragma unroll
    for (int d = 0; d < 12; ++d) v[d] = *(const float2*)&base[d * 64];
    act12p(qf, v, o);
#pragma unroll
    for (int d = 0; d < 12; ++d) *(float2*)&base[d * 64] = o[d];
}

// ---------------- MFMA bf16 lin (A fp32, B bf16). PE also writes hb -----
template <int PE>
__global__ __launch_bounds__(256) void k_lin4(const float* __restrict__ in,
                                              const unsigned short* __restrict__ Wb,
                                              const float* __restrict__ qfp,
                                              const float* __restrict__ pe,
                                              float* __restrict__ outv,
                                              unsigned short* __restrict__ hb) {
    const int d   = blockIdx.x;
    const int bs0 = blockIdx.y * 64;
    __shared__ unsigned short sA[64 * 72];
    __shared__ unsigned short sB[64 * 72];
    const int t  = threadIdx.x;
    const int w  = t >> 6;
    const int l  = t & 63;
    const int lr = l & 15;
    const int lk = l >> 4;

    f32x4 acc[4];
#pragma unroll
    for (int f = 0; f < 4; ++f) acc[f] = (f32x4){0.f, 0.f, 0.f, 0.f};

    const unsigned short* wbase = Wb + (size_t)d_REP[d] * 64 * 64;

    for (int e = t; e < 1024; e += 256) {
        int r = e >> 4, qq = e & 15;
        float4 v = *(const float4*)(in + ((size_t)(bs0 + r) * 12 + d) * 64 + qq * 4);
        ushort4 u = {f2bf(v.x), f2bf(v.y), f2bf(v.z), f2bf(v.w)};
        *(ushort4*)&sA[r * 72 + qq * 4] = u;
    }
    for (int e = t; e < 512; e += 256) {
        int c = e >> 3, seg = e & 7;
        *(bf16x8*)&sB[c * 72 + seg * 8] = *(const bf16x8*)(wbase + c * 64 + seg * 8);
    }
    __syncthreads();
#pragma unroll
    for (int ks = 0; ks < 2; ++ks) {
        bf16x8 a = *(const bf16x8*)&sA[(w * 16 + lr) * 72 + ks * 32 + lk * 8];
#pragma unroll
        for (int f = 0; f < 4; ++f) {
            bf16x8 b = *(const bf16x8*)&sB[(f * 16 + lr) * 72 + ks * 32 + lk * 8];
            acc[f] = __builtin_amdgcn_mfma_f32_16x16x32_bf16(a, b, acc[f], 0, 0, 0);
        }
    }

#pragma unroll
    for (int f = 0; f < 4; ++f) {
#pragma unroll
        for (int reg = 0; reg < 4; ++reg) {
            int bs = bs0 + w * 16 + lk * 4 + reg;
            int o  = f * 16 + lr;
            float val = acc[f][reg];
            size_t row = (size_t)bs * 12 + d;
            if (PE) val += qfp[144 + d] * pe[(bs & 511) * 64 + o];
            outv[row * 64 + o] = val;
            if (PE) hb[row * 64 + o] = f2bf(val);
        }
    }
}

// ---------------- wo-GEMM: A bf16 (attn out), B bf16, h +=, hb out ------
__global__ __launch_bounds__(256) void k_linwo(const unsigned short* __restrict__ t1b,
                                               const unsigned short* __restrict__ Wb,
                                               float* __restrict__ h,
                                               unsigned short* __restrict__ hb) {
    const int d   = blockIdx.x;
    const int bs0 = blockIdx.y * 64;
    __shared__ unsigned short sA[64 * 72];
    __shared__ unsigned short sB[64 * 72];
    const int t  = threadIdx.x;
    const int w  = t >> 6;
    const int l  = t & 63;
    const int lr = l & 15;
    const int lk = l >> 4;

    f32x4 acc[4];
#pragma unroll
    for (int f = 0; f < 4; ++f) acc[f] = (f32x4){0.f, 0.f, 0.f, 0.f};

    const unsigned short* wbase = Wb + (size_t)d_REP[d] * 64 * 64;

    for (int e = t; e < 512; e += 256) {
        int r = e >> 3, seg = e & 7;
        *(bf16x8*)&sA[r * 72 + seg * 8] =
            *(const bf16x8*)(t1b + ((size_t)(bs0 + r) * 12 + d) * 64 + seg * 8);
    }
    for (int e = t; e < 512; e += 256) {
        int c = e >> 3, seg = e & 7;
        *(bf16x8*)&sB[c * 72 + seg * 8] = *(const bf16x8*)(wbase + c * 64 + seg * 8);
    }
    __syncthreads();
#pragma unroll
    for (int ks = 0; ks < 2; ++ks) {
        bf16x8 a = *(const bf16x8*)&sA[(w * 16 + lr) * 72 + ks * 32 + lk * 8];
#pragma unroll
        for (int f = 0; f < 4; ++f) {
            bf16x8 b = *(const bf16x8*)&sB[(f * 16 + lr) * 72 + ks * 32 + lk * 8];
            acc[f] = __builtin_amdgcn_mfma_f32_16x16x32_bf16(a, b, acc[f], 0, 0, 0);
        }
    }

#pragma unroll
    for (int f = 0; f < 4; ++f) {
#pragma unroll
        for (int reg = 0; reg < 4; ++reg) {
            int bs = bs0 + w * 16 + lk * 4 + reg;
            int o  = f * 16 + lr;
            size_t row = (size_t)bs * 12 + d;
            float val = acc[f][reg] + h[row * 64 + o];
            h[row * 64 + o] = val;
            hb[row * 64 + o] = f2bf(val);
        }
    }
}

// ---------------- QKV projection (A = hb bf16, B bf16) ------------------
__global__ __launch_bounds__(256) void k_linqkv(const unsigned short* __restrict__ hbin,
                                                const unsigned short* __restrict__ wq,
                                                const unsigned short* __restrict__ wk,
                                                const unsigned short* __restrict__ wv,
                                                unsigned short* __restrict__ oq,
                                                unsigned short* __restrict__ ok,
                                                unsigned short* __restrict__ ov) {
    const int d   = blockIdx.x;
    const int bs0 = blockIdx.y * 64;
    __shared__ unsigned short sA[64 * 72];
    __shared__ unsigned short sB[64 * 72];
    const int t  = threadIdx.x;
    const int w  = t >> 6;
    const int l  = t & 63;
    const int lr = l & 15;
    const int lk = l >> 4;
    const int rep = d_REP[d];

    for (int e = t; e < 512; e += 256) {
        int r = e >> 3, seg = e & 7;
        *(bf16x8*)&sA[r * 72 + seg * 8] =
            *(const bf16x8*)(hbin + ((size_t)(bs0 + r) * 12 + d) * 64 + seg * 8);
    }

    for (int part = 0; part < 3; ++part) {
        const unsigned short* wsel = (part == 0) ? wq : (part == 1) ? wk : wv;
        const unsigned short* wbase = wsel + (size_t)rep * 64 * 64;
        __syncthreads();
        for (int e = t; e < 512; e += 256) {
            int c = e >> 3, seg = e & 7;
            *(bf16x8*)&sB[c * 72 + seg * 8] = *(const bf16x8*)(wbase + c * 64 + seg * 8);
        }
        __syncthreads();
        f32x4 acc[4];
#pragma unroll
        for (int f = 0; f < 4; ++f) acc[f] = (f32x4){0.f, 0.f, 0.f, 0.f};
#pragma unroll
        for (int ks = 0; ks < 2; ++ks) {
            bf16x8 a = *(const bf16x8*)&sA[(w * 16 + lr) * 72 + ks * 32 + lk * 8];
#pragma unroll
            for (int f = 0; f < 4; ++f) {
                bf16x8 b = *(const bf16x8*)&sB[(f * 16 + lr) * 72 + ks * 32 + lk * 8];
                acc[f] = __builtin_amdgcn_mfma_f32_16x16x32_bf16(a, b, acc[f], 0, 0, 0);
            }
        }
        unsigned short* oh = (part == 0) ? oq : (part == 1) ? ok : ov;
#pragma unroll
        for (int f = 0; f < 4; ++f) {
#pragma unroll
            for (int reg = 0; reg < 4; ++reg) {
                int bs = bs0 + w * 16 + lk * 4 + reg;
                int o  = f * 16 + lr;
                int b = bs >> 9, s = bs & 511;
                unsigned short hv = f2bf(acc[f][reg]);
                if (part < 2)
                    oh[(((size_t)(b * 8 + (o >> 3)) * 512 + s) * 96) + d * 8 + (o & 7)] = hv;
                else
                    oh[(((size_t)(b * 8 + (o >> 3)) * 96 + d * 8 + (o & 7)) * 512) + s] = hv;
            }
        }
    }
}

// ---------------- attention v7: 2-way split-K, 8 waves, 64 q-rows -------
// wave w: qgroup = w&3 (16 rows), ksplit = w>>2 (tiles 4*ks..4*ks+3).
// dual K/V buffers staged per iteration; linear softmax -> LDS combine.
#define SK_OFF 0                         // 2 x 64*104 ushort
#define SV_OFF (2 * 64 * 104)            // 2 x 96*72 ushort
#define PS_OFF (SV_OFF + 2 * 96 * 72)    // 8 x 16*72 ushort
__global__ __launch_bounds__(512) void k_attn7(const unsigned short* __restrict__ qh,
                                               const unsigned short* __restrict__ kh,
                                               const unsigned short* __restrict__ vt,
                                               unsigned short* __restrict__ out) {
    __shared__ unsigned short smem[PS_OFF + 8 * 16 * 72];   // 72704 B
    unsigned short* sK = smem + SK_OFF;
    unsigned short* sV = smem + SV_OFF;
    unsigned short* ps = smem + PS_OFF;
    const int bh = blockIdx.x >> 3;
    const int q0 = (blockIdx.x & 7) * 64;
    const int t = threadIdx.x;
    const int w = t >> 6;
    const int l = t & 63;
    const int lr = l & 15;
    const int lk = l >> 4;
    const int qg = w & 3;
    const int ks2 = w >> 2;

    const unsigned short* qgp = qh + ((size_t)bh * 512 + q0 + qg * 16) * 96;
    bf16x8 qa[3];
#pragma unroll
    for (int ks = 0; ks < 3; ++ks)
        qa[ks] = *(const bf16x8*)(qgp + (size_t)lr * 96 + ks * 32 + lk * 8);

    float ts[4] = {0.f, 0.f, 0.f, 0.f};
    f32x4 o[6];
#pragma unroll
    for (int f = 0; f < 6; ++f) o[f] = (f32x4){0.f, 0.f, 0.f, 0.f};

    const unsigned short* kg = kh + (size_t)bh * 512 * 96;
    const unsigned short* vg = vt + (size_t)bh * 96 * 512;
    const float scale = 0.10206207261596577f;   // 1/sqrt(96)

    for (int it = 0; it < 4; ++it) {
        __syncthreads();
        // stage tile it -> buf0 and tile it+4 -> buf1 (512 threads)
        for (int e = t; e < 1536; e += 512) {
            int buf = e >= 768;
            int e2 = e - buf * 768;
            int row = e2 / 12, seg = e2 % 12;
            int tile = it + buf * 4;
            *(bf16x8*)&sK[buf * 64 * 104 + row * 104 + seg * 8] =
                *(const bf16x8*)(kg + ((size_t)(tile * 64 + row)) * 96 + seg * 8);
        }
        for (int e = t; e < 1536; e += 512) {
            int buf = e >= 768;
            int e2 = e - buf * 768;
            int row = e2 / 8, seg = e2 % 8;
            int tile = it + buf * 4;
            *(bf16x8*)&sV[buf * 96 * 72 + row * 72 + seg * 8] =
                *(const bf16x8*)(vg + (size_t)row * 512 + tile * 64 + seg * 8);
        }
        __syncthreads();

        const unsigned short* myK = sK + ks2 * 64 * 104;
        const unsigned short* myV = sV + ks2 * 96 * 72;

#pragma unroll
        for (int f = 0; f < 4; ++f) {
            f32x4 acc = {0.f, 0.f, 0.f, 0.f};
#pragma unroll
            for (int ks = 0; ks < 3; ++ks) {
                bf16x8 kb = *(const bf16x8*)&myK[(f * 16 + lr) * 104 + ks * 32 + lk * 8];
                acc = __builtin_amdgcn_mfma_f32_16x16x32_bf16(qa[ks], kb, acc, 0, 0, 0);
            }
#pragma unroll
            for (int r = 0; r < 4; ++r) {
                float p = __expf(acc[r] * scale);
                ts[r] += p;
                ps[w * 16 * 72 + (lk * 4 + r) * 72 + f * 16 + lr] = f2bf(p);
            }
        }

        bf16x8 pa[2];
#pragma unroll
        for (int ks = 0; ks < 2; ++ks)
            pa[ks] = *(const bf16x8*)&ps[w * 16 * 72 + lr * 72 + ks * 32 + lk * 8];
#pragma unroll
        for (int f = 0; f < 6; ++f) {
            f32x4 acc = o[f];
#pragma unroll
            for (int ks = 0; ks < 2; ++ks) {
                bf16x8 vb = *(const bf16x8*)&myV[(f * 16 + lr) * 72 + ks * 32 + lk * 8];
                acc = __builtin_amdgcn_mfma_f32_16x16x32_bf16(pa[ks], vb, acc, 0, 0, 0);
            }
            o[f] = acc;
        }
    }

    // ---- combine the two k-splits (alias over sK/sV region) ----
    __syncthreads();
    float* cbuf = (float*)smem;                 // [4][64][29] floats = 29696 B
    if (ks2 == 1) {
        float* dst = cbuf + ((size_t)qg * 64 + l) * 29;
#pragma unroll
        for (int f = 0; f < 6; ++f) {
#pragma unroll
            for (int r = 0; r < 4; ++r) dst[f * 4 + r] = o[f][r];
        }
#pragma unroll
        for (int r = 0; r < 4; ++r) dst[24 + r] = ts[r];
    }
    __syncthreads();
    if (ks2 == 0) {
        const float* src = cbuf + ((size_t)qg * 64 + l) * 29;
#pragma unroll
        for (int f = 0; f < 6; ++f)
#pragma unroll
            for (int r = 0; r < 4; ++r) o[f][r] += src[f * 4 + r];
#pragma unroll
        for (int r = 0; r < 4; ++r) ts[r] += src[24 + r];

        float inv[4];
#pragma unroll
        for (int r = 0; r < 4; ++r) {
            float s2 = ts[r];
#pragma unroll
            for (int d = 1; d < 16; d <<= 1) s2 += __shfl_xor(s2, d);
            inv[r] = 1.0f / s2;
        }
        const int b = bh >> 3, hh = bh & 7;
#pragma unroll
        for (int r = 0; r < 4; ++r) {
            int s = q0 + qg * 16 + lk * 4 + r;
            unsigned short* ob = out + ((size_t)(b * 512 + s) * 12) * 64 + hh * 8;
#pragma unroll
            for (int f = 0; f < 6; ++f) {
                int col = f * 16 + lr;
                ob[(col >> 3) * 64 + (col & 7)] = f2bf(o[f][r] * inv[r]);
            }
        }
    }
}

// ---------------- fused f1-GEMM + act (packed) -> bf16 fmid -------------
__global__ __launch_bounds__(256, 4) void k_f1act(const unsigned short* __restrict__ hb,
                                                  const unsigned short* __restrict__ f1wb,
                                                  const float* __restrict__ qf,
                                                  unsigned short* __restrict__ fmidb) {
    constexpr int S_[7]  = {0, 1, 2, 4, 6, 8, 10};
    constexpr int DKv[7] = {1, 1, 2, 2, 2, 2, 2};
    const int bs0 = blockIdx.x * 16;
    const int c0  = blockIdx.y * 64;
    __shared__ unsigned short sB[64 * 72];
    const int t  = threadIdx.x;
    const int w  = t >> 6;      // wave = col fragment
    const int l  = t & 63;
    const int lr = l & 15;
    const int lk = l >> 4;

    f32x4 acc[12];
#pragma unroll
    for (int d = 0; d < 12; ++d) acc[d] = (f32x4){0.f, 0.f, 0.f, 0.f};

    const unsigned short* arow = hb + (size_t)(bs0 + lr) * 12 * 64 + lk * 8;

#pragma unroll
    for (int k = 0; k < 7; ++k) {
        if (k) __syncthreads();
        const unsigned short* wbase = f1wb + ((size_t)k * 256 + c0) * 64;
        for (int e = t; e < 512; e += 256) {
            int c = e >> 3, seg = e & 7;
            *(bf16x8*)&sB[c * 72 + seg * 8] = *(const bf16x8*)(wbase + c * 64 + seg * 8);
        }
        __syncthreads();
#pragma unroll
        for (int dd = 0; dd < 2; ++dd) {
            if (dd < DKv[k]) {
                int d = S_[k] + dd;
#pragma unroll
                for (int ks = 0; ks < 2; ++ks) {
                    bf16x8 a = *(const bf16x8*)(arow + (size_t)d * 64 + ks * 32);
                    bf16x8 b = *(const bf16x8*)&sB[(w * 16 + lr) * 72 + ks * 32 + lk * 8];
                    acc[d] = __builtin_amdgcn_mfma_f32_16x16x32_bf16(a, b, acc[d], 0, 0, 0);
                }
            }
        }
    }

    // packed act in registers + bf16 store (no barriers in this phase)
    int col = c0 + w * 16 + lr;
#pragma unroll
    for (int pp = 0; pp < 2; ++pp) {
        float2 v[12], o[12];
#pragma unroll
        for (int d = 0; d < 12; ++d) v[d] = make_float2(acc[d][pp * 2], acc[d][pp * 2 + 1]);
        act12p(qf, v, o);
        int row = bs0 + lk * 4 + pp * 2;
#pragma unroll
        for (int d = 0; d < 12; ++d) {
            fmidb[((size_t)row * 12 + d) * 256 + col]       = f2bf(o[d].x);
            fmidb[((size_t)(row + 1) * 12 + d) * 256 + col] = f2bf(o[d].y);
        }
    }
}

// ---------------- fused f2-GEMM (+res, h out) + next-layer QKV ----------
template <int QKV>
__global__ __launch_bounds__(256) void k_f2qkv(const unsigned short* __restrict__ inb,
                                               const unsigned short* __restrict__ Wf2,
                                               const unsigned short* __restrict__ wq,
                                               const unsigned short* __restrict__ wk,
                                               const unsigned short* __restrict__ wv,
                                               float* __restrict__ h,
                                               unsigned short* __restrict__ oq,
                                               unsigned short* __restrict__ ok,
                                               unsigned short* __restrict__ ov) {
    const int d   = blockIdx.x;
    const int bs0 = blockIdx.y * 64;
    __shared__ unsigned short sA[64 * 72];
    __shared__ unsigned short sB[64 * 72];
    __shared__ unsigned short sH[64 * 72];
    const int t  = threadIdx.x;
    const int w  = t >> 6;
    const int l  = t & 63;
    const int lr = l & 15;
    const int lk = l >> 4;
    const int rep = d_REP[d];

    f32x4 acc[4];
#pragma unroll
    for (int f = 0; f < 4; ++f) acc[f] = (f32x4){0.f, 0.f, 0.f, 0.f};

    const unsigned short* wbase = Wf2 + (size_t)rep * 64 * 256;

    // phase 1: h' = fmid * f2 + h
    for (int kc = 0; kc < 256; kc += 64) {
        __syncthreads();
        for (int e = t; e < 512; e += 256) {
            int r = e >> 3, seg = e & 7;
            *(bf16x8*)&sA[r * 72 + seg * 8] =
                *(const bf16x8*)(inb + ((size_t)(bs0 + r) * 12 + d) * 256 + kc + seg * 8);
        }
        for (int e = t; e < 512; e += 256) {
            int c = e >> 3, seg = e & 7;
            *(bf16x8*)&sB[c * 72 + seg * 8] =
                *(const bf16x8*)(wbase + (size_t)c * 256 + kc + seg * 8);
        }
        __syncthreads();
#pragma unroll
        for (int ks = 0; ks < 2; ++ks) {
            bf16x8 a = *(const bf16x8*)&sA[(w * 16 + lr) * 72 + ks * 32 + lk * 8];
#pragma unroll
            for (int f = 0; f < 4; ++f) {
                bf16x8 b = *(const bf16x8*)&sB[(f * 16 + lr) * 72 + ks * 32 + lk * 8];
                acc[f] = __builtin_amdgcn_mfma_f32_16x16x32_bf16(a, b, acc[f], 0, 0, 0);
            }
        }
    }

#pragma unroll
    for (int f = 0; f < 4; ++f) {
#pragma unroll
        for (int reg = 0; reg < 4; ++reg) {
            int rloc = w * 16 + lk * 4 + reg;
            int bs = bs0 + rloc;
            int o  = f * 16 + lr;
            size_t row = (size_t)bs * 12 + d;
            float val = acc[f][reg] + h[row * 64 + o];
            h[row * 64 + o] = val;
            if (QKV) sH[rloc * 72 + o] = f2bf(val);
        }
    }

    // phase 2: QKV for the next layer from sH
    if (QKV) {
        for (int part = 0; part < 3; ++part) {
            const unsigned short* wsel = (part == 0) ? wq : (part == 1) ? wk : wv;
            const unsigned short* wb2 = wsel + (size_t)rep * 64 * 64;
            __syncthreads();
            for (int e = t; e < 512; e += 256) {
                int c = e >> 3, seg = e & 7;
                *(bf16x8*)&sB[c * 72 + seg * 8] = *(const bf16x8*)(wb2 + c * 64 + seg * 8);
            }
            __syncthreads();
            f32x4 a2[4];
#pragma unroll
            for (int f = 0; f < 4; ++f) a2[f] = (f32x4){0.f, 0.f, 0.f, 0.f};
#pragma unroll
            for (int ks = 0; ks < 2; ++ks) {
                bf16x8 a = *(const bf16x8*)&sH[(w * 16 + lr) * 72 + ks * 32 + lk * 8];
#pragma unroll
                for (int f = 0; f < 4; ++f) {
                    bf16x8 b = *(const bf16x8*)&sB[(f * 16 + lr) * 72 + ks * 32 + lk * 8];
                    a2[f] = __builtin_amdgcn_mfma_f32_16x16x32_bf16(a, b, a2[f], 0, 0, 0);
                }
            }
            unsigned short* oh = (part == 0) ? oq : (part == 1) ? ok : ov;
#pragma unroll
            for (int f = 0; f < 4; ++f) {
#pragma unroll
                for (int reg = 0; reg < 4; ++reg) {
                    int bs = bs0 + w * 16 + lk * 4 + reg;
                    int o  = f * 16 + lr;
                    int b = bs >> 9, s = bs & 511;
                    unsigned short hv = f2bf(a2[f][reg]);
                    if (part < 2)
                        oh[(((size_t)(b * 8 + (o >> 3)) * 512 + s) * 96) + d * 8 + (o & 7)] = hv;
                    else
                        oh[(((size_t)(b * 8 + (o >> 3)) * 96 + d * 8 + (o & 7)) * 512) + s] = hv;
                }
            }
        }
    }
}

// ---------------- fc_out (decoder tail) ----------------
__global__ void k_fcout(const float* __restrict__ h, const float* __restrict__ w,
                        const float* __restrict__ qf, float* __restrict__ z) {
    int bs = blockIdx.x;
    __shared__ float td[12];
    int t = threadIdx.x;
    if (t < 12) {
        const float* row = h + ((size_t)bs * 12 + t) * 64;
        const float* wr  = w + d_REP[t] * 64;
        float a = 0.f;
        for (int i = 0; i < 64; ++i) a += row[i] * wr[i];
        td[t] = a;
    }
    __syncthreads();
    if (t < 12) {
        float a = 0.f;
        for (int d = 0; d < 12; ++d) a += qf[d * 12 + t] * td[d];
        z[bs * 12 + t] = a / 7.0f;
    }
}

// ---------------- fused fc_out + VQ (encoder tail) ----------------------
__global__ __launch_bounds__(256) void k_fcvq(const float* __restrict__ h,
                                              const float* __restrict__ w,
                                              const float* __restrict__ qf,
                                              const float* __restrict__ cb,
                                              float* __restrict__ z,
                                              float* __restrict__ zvq,
                                              float* __restrict__ zst) {
    int bs = blockIdx.x;
    int t = threadIdx.x;
    __shared__ float td[12];
    __shared__ float zv[12];
    __shared__ float sb[256];
    __shared__ int   si[256];
    if (t < 12) {
        const float* row = h + ((size_t)bs * 12 + t) * 64;
        const float* wr  = w + d_REP[t] * 64;
        float a = 0.f;
        for (int i = 0; i < 64; ++i) a += row[i] * wr[i];
        td[t] = a;
    }
    __syncthreads();
    if (t < 12) {
        float a = 0.f;
        for (int d = 0; d < 12; ++d) a += qf[d * 12 + t] * td[d];
        a /= 7.0f;
        zv[t] = a;
        z[bs * 12 + t] = a;
    }
    __syncthreads();
    float zz = 0.f;
    for (int j = 0; j < 12; ++j) zz += zv[j] * zv[j];
    float best = 3.4e38f; int bi = 0x7fffffff;
    for (int c = t; c < KCB; c += 256) {
        const float* cr = cb + c * 12;
        float cc = 0.f, dot = 0.f;
        for (int j = 0; j < 12; ++j) { cc += cr[j] * cr[j]; dot += zv[j] * cr[j]; }
        float dist = zz + cc - 2.0f * dot;
        if (dist < best) { best = dist; bi = c; }
    }
    sb[t] = best; si[t] = bi; __syncthreads();
    for (int st = 128; st > 0; st >>= 1) {
        if (t < st) {
            if (sb[t + st] < sb[t] || (sb[t + st] == sb[t] && si[t + st] < si[t])) {
                sb[t] = sb[t + st]; si[t] = si[t + st];
            }
        }
        __syncthreads();
    }
    if (t < 12) {
        float c = cb[si[0] * 12 + t];
        zvq[bs * 12 + t] = c;
        float zi = zv[t];
        zst[bs * 12 + t] = (c - zi) + zi;
    }
}

// ---------------- merged losses ----------------
__global__ __launch_bounds__(256) void k_loss(const float* __restrict__ x,
                                              const float* __restrict__ logits,
                                              const float* __restrict__ z,
                                              const float* __restrict__ zvq,
                                              float* __restrict__ xr_out,
                                              float* __restrict__ p1,
                                              float* __restrict__ p2) {
    __shared__ float red[256];
    int t = threadIdx.x;
    float acc1 = 0.f, acc2 = 0.f;
    for (int i = blockIdx.x * 256 + t; i < NEL; i += gridDim.x * 256) {
        float lg = logits[i];
        float xr = 1.0f / (1.0f + expf(-lg));
        xr_out[i] = xr;
        float xi = x[i];
        float l1 = fmaxf(logf(xr), -100.0f);
        float l2 = fmaxf(logf(1.0f - xr), -100.0f);
        acc1 += xi * l1 + (1.0f - xi) * l2;
        float dd = zvq[i] - z[i];
        acc2 += dd * dd;
    }
    red[t] = acc1; __syncthreads();
    for (int st = 128; st > 0; st >>= 1) { if (t < st) red[t] += red[t + st]; __syncthreads(); }
    if (t == 0) p1[blockIdx.x] = red[0];
    __syncthreads();
    red[t] = acc2; __syncthreads();
    for (int st = 128; st > 0; st >>= 1) { if (t < st) red[t] += red[t + st]; __syncthreads(); }
    if (t == 0) p2[blockIdx.x] = red[0];
}

__global__ void k_final(const float* __restrict__ p1, const float* __restrict__ p2,
                        float* __restrict__ out) {
    if (threadIdx.x == 0) {
        float s1 = 0.f, s2 = 0.f;
        for (int i = 0; i < 96; ++i) { s1 += p1[i]; s2 += p2[i]; }
        out[NEL]     = -s1 / (float)NEL;
        out[NEL + 1] =  s2 / (float)NEL;
        out[NEL + 2] =  s2 / (float)NEL;
    }
}

// ------------------------------------------------------------------------
extern "C" void kernel_launch(void* const* d_in, const int* in_sizes, int n_in,
                              void* d_out, int out_size, void* d_ws, size_t ws_size,
                              hipStream_t stream) {
    const float* x   = (const float*)d_in[0];
    const float* efb = (const float*)d_in[1];
    const float* efw = (const float*)d_in[2];
    const float* ew1 = (const float*)d_in[3];
    const float* ew2 = (const float*)d_in[4];
    const float* ew3 = (const float*)d_in[5];
    const float* ewq = (const float*)d_in[6];
    const float* ewk = (const float*)d_in[7];
    const float* ewv = (const float*)d_in[8];
    const float* ewo = (const float*)d_in[9];
    const float* ef1 = (const float*)d_in[10];
    const float* ef2 = (const float*)d_in[11];
    const float* eow = (const float*)d_in[12];
    const float* cb  = (const float*)d_in[13];
    const float* dfb = (const float*)d_in[14];
    const float* dfw = (const float*)d_in[15];
    const float* dw1 = (const float*)d_in[16];
    const float* dw2 = (const float*)d_in[17];
    const float* dw3 = (const float*)d_in[18];
    const float* dwq = (const float*)d_in[19];
    const float* dwk = (const float*)d_in[20];
    const float* dwv = (const float*)d_in[21];
    const float* dwo = (const float*)d_in[22];
    const float* df1 = (const float*)d_in[23];
    const float* df2 = (const float*)d_in[24];
    const float* dow = (const float*)d_in[25];
    float* out = (float*)d_out;

    float* ws = (float*)d_ws;
    float* qf   = ws;                           // 512
    float* h    = ws + 512;                     // 3,145,728
    float* fmid = h + 3145728;                  // 12,582,912 region (bf16 fmid + q/kk/vv aliases)
    float* t1   = fmid + 12582912;              // 3,145,728 (fp32 head tmp; bf16 attn-out alias)
    float* z    = t1 + 3145728;
    float* zvq  = z + NEL;
    float* zst  = zvq + NEL;
    float* z2   = zst + NEL;
    float* p1   = z2 + NEL;
    float* p2   = p1 + 128;
    float* pe   = p2 + 128;                     // 32768
    unsigned short* wb = (unsigned short*)(pe + 32768);               // 1,433,600 ushorts
    unsigned short* hb = wb + WB_TOTAL;                               // 3,145,728 ushorts
    unsigned short* fmidb = (unsigned short*)fmid;                    // 12.6M ushorts
    unsigned short* q  = (unsigned short*)(fmid + 6291456);           // after fmidb
    unsigned short* kk = q + 3145728;
    unsigned short* vv = kk + 3145728;
    unsigned short* t1b = (unsigned short*)t1;

    auto run_half = [&](const float* xin, const float* fb, const float* fw,
                        const float* w1, const float* w2, const float* w3,
                        const float* wq, const float* wk, const float* wv,
                        const float* wo, const float* f1, const float* f2) {
        k_cvtw<<<1400, 256, 0, stream>>>(w2, w3, wq, wk, wv, wo, f1, f2, wb);
        k_embact<<<BSN / 4, 256, 0, stream>>>(xin, fb, fw, w1, qf, h);
        k_lin4<0><<<dim3(12, 64), 256, 0, stream>>>(h, wb + OB_W2, qf, nullptr, t1, nullptr);
        k_act<<<(BSN * 32 + 255) / 256, 256, 0, stream>>>(t1, qf);
        k_lin4<1><<<dim3(12, 64), 256, 0, stream>>>(t1, wb + OB_W3, qf, pe, h, hb);
        k_linqkv<<<dim3(12, 64), 256, 0, stream>>>(hb, wb + OB_WQ, wb + OB_WK, wb + OB_WV, q, kk, vv);
        for (int l = 0; l < LLAY; ++l) {
            const unsigned short* wbo  = wb + OB_WO + (size_t)l * 28672;
            const unsigned short* wbf1 = wb + OB_F1 + (size_t)l * 114688;
            const unsigned short* wbf2 = wb + OB_F2 + (size_t)l * 114688;
            k_attn7<<<BB * HHEAD * 8, 512, 0, stream>>>(q, kk, vv, t1b);
            k_linwo<<<dim3(12, 64), 256, 0, stream>>>(t1b, wbo, h, hb);
            k_f1act<<<dim3(256, 4), 256, 0, stream>>>(hb, wbf1, qf, fmidb);
            if (l < LLAY - 1) {
                const unsigned short* wbq = wb + OB_WQ + (size_t)(l + 1) * 28672;
                const unsigned short* wbk = wb + OB_WK + (size_t)(l + 1) * 28672;
                const unsigned short* wbv = wb + OB_WV + (size_t)(l + 1) * 28672;
                k_f2qkv<1><<<dim3(12, 64), 256, 0, stream>>>(fmidb, wbf2, wbq, wbk, wbv, h, q, kk, vv);
            } else {
                k_f2qkv<0><<<dim3(12, 64), 256, 0, stream>>>(fmidb, wbf2, nullptr, nullptr, nullptr, h, nullptr, nullptr, nullptr);
            }
        }
    };

    k_init_qf<<<1, 256, 0, stream>>>(qf);
    k_init_pe<<<512, 64, 0, stream>>>(pe);
    run_half(x, efb, efw, ew1, ew2, ew3, ewq, ewk, ewv, ewo, ef1, ef2);
    k_fcvq<<<BSN, 256, 0, stream>>>(h, eow, qf, cb, z, zvq, zst);
    run_half(zst, dfb, dfw, dw1, dw2, dw3, dwq, dwk, dwv, dwo, df1, df2);
    k_fcout<<<BSN, 64, 0, stream>>>(h, dow, qf, z2);
    k_loss<<<96, 256, 0, stream>>>(x, z2, z, zvq, out, p1, p2);
    k_final<<<1, 64, 0, stream>>>(p1, p2, out);
}

// Round 15
// 901.669 us; speedup vs baseline: 1.0720x; 1.0059x over previous
//
#include <hip/hip_runtime.h>
#include <math.h>

#define BB 8
#define SS 512
#define HHEAD 8
#define LLAY 4
#define KCB 1024
#define BSN 4096          // B*S
#define ROWS 49152        // BS*12
#define NEL 49152         // B*S*12

__constant__ int d_REP[12] = {0,1,2,2,3,3,4,4,5,5,6,6};

typedef __attribute__((ext_vector_type(8))) short bf16x8;
typedef __attribute__((ext_vector_type(4))) float f32x4;

// bf16 weight-region offsets (ushorts) inside wb
#define OB_W2 0
#define OB_W3 28672
#define OB_WQ 57344        // + l*28672
#define OB_WK 172032
#define OB_WV 286720
#define OB_WO 401408
#define OB_F1 516096       // + l*114688
#define OB_F2 974848
#define WB_TOTAL 1433600

__device__ inline unsigned short f2bf(float x) {
    unsigned u = __builtin_bit_cast(unsigned, x);
    u += 0x7FFF + ((u >> 16) & 1);
    return (unsigned short)(u >> 16);
}

// fast gelu: erf via Abramowitz-Stegun 7.1.26 (|err| < 1.5e-7), HW rcp
__device__ inline float fast_gelu(float a) {
    float x = a * 0.7071067811865475f;
    float ax = fabsf(x);
    float tt = __builtin_amdgcn_rcpf(fmaf(0.3275911f, ax, 1.0f));
    float poly = ((((1.061405429f * tt - 1.453152027f) * tt + 1.421413741f) * tt
                   - 0.284496736f) * tt + 0.254829592f) * tt;
    float y = fmaf(-poly, __expf(-x * x), 1.0f);
    return 0.5f * a * (1.0f + copysignf(y, x));
}

// packed (float2) gelu
__device__ inline float2 fast_gelu2(float2 a) {
    float2 x  = make_float2(a.x * 0.7071067811865475f, a.y * 0.7071067811865475f);
    float2 tt = make_float2(
        __builtin_amdgcn_rcpf(fmaf(0.3275911f, fabsf(x.x), 1.0f)),
        __builtin_amdgcn_rcpf(fmaf(0.3275911f, fabsf(x.y), 1.0f)));
    float2 p = make_float2(fmaf(1.061405429f, tt.x, -1.453152027f),
                           fmaf(1.061405429f, tt.y, -1.453152027f));
    p = make_float2(fmaf(p.x, tt.x, 1.421413741f),  fmaf(p.y, tt.y, 1.421413741f));
    p = make_float2(fmaf(p.x, tt.x, -0.284496736f), fmaf(p.y, tt.y, -0.284496736f));
    p = make_float2(fmaf(p.x, tt.x, 0.254829592f),  fmaf(p.y, tt.y, 0.254829592f));
    p = make_float2(p.x * tt.x, p.y * tt.y);
    float2 ex = make_float2(__expf(-x.x * x.x), __expf(-x.y * x.y));
    float2 y  = make_float2(fmaf(-p.x, ex.x, 1.0f), fmaf(-p.y, ex.y, 1.0f));
    float2 er = make_float2(copysignf(y.x, x.x), copysignf(y.y, x.y));
    return make_float2(0.5f * a.x * (1.0f + er.x), 0.5f * a.y * (1.0f + er.y));
}

// symmetry-reduced act on one 12-vector (tables in qf[160..] / qf[256..])
__device__ inline void act12(const float* __restrict__ qf, const float v[12], float o[12]) {
    constexpr int S_[7]  = {0, 1, 2, 4, 6, 8, 10};
    constexpr int DKv[7] = {1, 1, 2, 2, 2, 2, 2};
    constexpr int P_[7]  = {1, 2, 12, 6, 4, 3, 12};
    constexpr int UO[7]  = {0, 1, 3, 15, 21, 25, 28};
    constexpr int OO[7]  = {0, 1, 3, 27, 39, 47, 53};
    const float* QP = qf + 160;
    const float* QO = qf + 256;
#pragma unroll
    for (int k = 0; k < 7; ++k) {
        float g[12];
#pragma unroll
        for (int u = 0; u < P_[k]; ++u) {
            float p = QP[(UO[k] + u) * 2] * v[S_[k]];
            if (DKv[k] == 2) p = fmaf(QP[(UO[k] + u) * 2 + 1], v[S_[k] + 1], p);
            g[u] = fast_gelu(p);
        }
#pragma unroll
        for (int d = 0; d < DKv[k]; ++d) {
            float a = 0.f;
#pragma unroll
            for (int u = 0; u < P_[k]; ++u) a = fmaf(QO[OO[k] + d * P_[k] + u], g[u], a);
            o[S_[k] + d] = a;
        }
    }
}

// packed act: two independent positions per call
__device__ inline void act12p(const float* __restrict__ qf, const float2 v[12], float2 o[12]) {
    constexpr int S_[7]  = {0, 1, 2, 4, 6, 8, 10};
    constexpr int DKv[7] = {1, 1, 2, 2, 2, 2, 2};
    constexpr int P_[7]  = {1, 2, 12, 6, 4, 3, 12};
    constexpr int UO[7]  = {0, 1, 3, 15, 21, 25, 28};
    constexpr int OO[7]  = {0, 1, 3, 27, 39, 47, 53};
    const float* QP = qf + 160;
    const float* QO = qf + 256;
#pragma unroll
    for (int k = 0; k < 7; ++k) {
        float2 g[12];
#pragma unroll
        for (int u = 0; u < P_[k]; ++u) {
            float c0 = QP[(UO[k] + u) * 2];
            float2 p = make_float2(c0 * v[S_[k]].x, c0 * v[S_[k]].y);
            if (DKv[k] == 2) {
                float c1 = QP[(UO[k] + u) * 2 + 1];
                p = make_float2(fmaf(c1, v[S_[k] + 1].x, p.x), fmaf(c1, v[S_[k] + 1].y, p.y));
            }
            g[u] = fast_gelu2(p);
        }
#pragma unroll
        for (int d = 0; d < DKv[k]; ++d) {
            float2 a = make_float2(0.f, 0.f);
#pragma unroll
            for (int u = 0; u < P_[k]; ++u) {
                float c = QO[OO[k] + d * P_[k] + u];
                a = make_float2(fmaf(c, g[u].x, a.x), fmaf(c, g[u].y, a.y));
            }
            o[S_[k] + d] = a;
        }
    }
}

// ---------------- QF init + rowsums + reduced act tables ----------------
__global__ void k_init_qf(float* qf) {
    int t = threadIdx.x;
    if (t < 144) {
        int r = t / 12, j = t % 12;
        double v;
        if (r == 0)      v = 1.0 / sqrt(12.0);
        else if (r == 1) v = ((j & 1) ? -1.0 : 1.0) / sqrt(12.0);
        else {
            int m = r >> 1;
            double ang = 2.0 * 3.14159265358979323846 * (double)m * (double)j / 12.0;
            v = (((r & 1) == 0) ? cos(ang) : sin(ang)) / sqrt(6.0);
        }
        qf[t] = (float)v;
    }
    __syncthreads();
    if (t < 12) {
        float s = 0.f;
        for (int j = 0; j < 12; ++j) s += qf[t * 12 + j];
        qf[144 + t] = s;
    }
    __syncthreads();
    if (t == 0) {
        const int S_[7]  = {0, 1, 2, 4, 6, 8, 10};
        const int DKv[7] = {1, 1, 2, 2, 2, 2, 2};
        const int P_[7]  = {1, 2, 12, 6, 4, 3, 12};
        const int UO[7]  = {0, 1, 3, 15, 21, 25, 28};
        const int OO[7]  = {0, 1, 3, 27, 39, 47, 53};
        for (int k = 0; k < 7; ++k) {
            for (int u = 0; u < P_[k]; ++u) {
                qf[160 + (UO[k] + u) * 2]     = qf[S_[k] * 12 + u];
                qf[160 + (UO[k] + u) * 2 + 1] = (DKv[k] == 2) ? qf[(S_[k] + 1) * 12 + u] : 0.f;
            }
            for (int d = 0; d < DKv[k]; ++d)
                for (int u = 0; u < P_[k]; ++u) {
                    float a = 0.f;
                    for (int pp = u; pp < 12; pp += P_[k]) a += qf[(S_[k] + d) * 12 + pp];
                    qf[256 + OO[k] + d * P_[k] + u] = a;
                }
        }
    }
}

// ---------------- pe table [512][64] ----------------
__global__ void k_init_pe(float* pe) {
    int s = blockIdx.x, m = threadIdx.x;
    int i = m >> 1;
    float dv = expf((float)(2 * i) * (-0.14391156831212787f));
    float arg = (float)s * dv;
    pe[s * 64 + m] = (m & 1) ? cosf(arg) : sinf(arg);
}

// ---------------- weight bf16 pre-conversion (one half) -----------------
__global__ __launch_bounds__(256) void k_cvtw(const float* __restrict__ w2,
                                              const float* __restrict__ w3,
                                              const float* __restrict__ wq,
                                              const float* __restrict__ wk,
                                              const float* __restrict__ wv,
                                              const float* __restrict__ wo,
                                              const float* __restrict__ f1,
                                              const float* __restrict__ f2,
                                              unsigned short* __restrict__ dst) {
    int i = blockIdx.x * 256 + threadIdx.x;   // float4 index
    const float* src; int off;
    if      (i <   7168) { src = w2; off = i; }
    else if (i <  14336) { src = w3; off = i -   7168; }
    else if (i <  43008) { src = wq; off = i -  14336; }
    else if (i <  71680) { src = wk; off = i -  43008; }
    else if (i < 100352) { src = wv; off = i -  71680; }
    else if (i < 129024) { src = wo; off = i - 100352; }
    else if (i < 243712) { src = f1; off = i - 129024; }
    else if (i < 358400) { src = f2; off = i - 243712; }
    else return;
    float4 v = ((const float4*)src)[off];
    ushort4 u = {f2bf(v.x), f2bf(v.y), f2bf(v.z), f2bf(v.w)};
    *(ushort4*)(dst + (size_t)i * 4) = u;
}

// ---------------- fused embed + act64 -> bf16: 4 bs per block -----------
__global__ __launch_bounds__(256) void k_embact(const float* __restrict__ x,
                                                const float* __restrict__ fb,
                                                const float* __restrict__ fw,
                                                const float* __restrict__ w1,
                                                const float* __restrict__ qf,
                                                unsigned short* __restrict__ eb) {
    int bs0 = blockIdx.x * 4;
    int t = threadIdx.x;
    __shared__ float xs[4][12], h1[4][12];
    if (t < 48) {
        int sb = t / 12, j = t % 12;
        xs[sb][j] = x[(bs0 + sb) * 12 + j] + fb[0];
    }
    __syncthreads();
    if (t < 48) {
        int sb = t / 12, j = t % 12;
        float a = 0.f;
        for (int p = 0; p < 12; ++p) a += qf[j * 12 + p] * xs[sb][p];
        h1[sb][j] = a * fw[0];
    }
    __syncthreads();
    int sb = t >> 6, m = t & 63;
    float v[12], o[12];
#pragma unroll
    for (int d = 0; d < 12; ++d) v[d] = h1[sb][d] * w1[d_REP[d] * 64 + m];
    act12(qf, v, o);
    unsigned short* ob = eb + ((size_t)(bs0 + sb) * 12) * 64 + m;
#pragma unroll
    for (int d = 0; d < 12; ++d) ob[d * 64] = f2bf(o[d]);
}

// ---------------- fused w2-GEMM + act -> bf16 (f1act structure) ---------
// grid (256): 16 rows x 64 cols, loop d with 7 rep-grouped B panels.
__global__ __launch_bounds__(256, 4) void k_w2act(const unsigned short* __restrict__ eb,
                                                  const unsigned short* __restrict__ w2b,
                                                  const float* __restrict__ qf,
                                                  unsigned short* __restrict__ t1c) {
    constexpr int S_[7]  = {0, 1, 2, 4, 6, 8, 10};
    constexpr int DKv[7] = {1, 1, 2, 2, 2, 2, 2};
    const int bs0 = blockIdx.x * 16;
    __shared__ unsigned short sB[64 * 72];
    const int t  = threadIdx.x;
    const int w  = t >> 6;
    const int l  = t & 63;
    const int lr = l & 15;
    const int lk = l >> 4;

    f32x4 acc[12];
#pragma unroll
    for (int d = 0; d < 12; ++d) acc[d] = (f32x4){0.f, 0.f, 0.f, 0.f};

    const unsigned short* arow = eb + (size_t)(bs0 + lr) * 12 * 64 + lk * 8;

#pragma unroll
    for (int k = 0; k < 7; ++k) {
        if (k) __syncthreads();
        const unsigned short* wbase = w2b + (size_t)k * 64 * 64;
        for (int e = t; e < 512; e += 256) {
            int c = e >> 3, seg = e & 7;
            *(bf16x8*)&sB[c * 72 + seg * 8] = *(const bf16x8*)(wbase + c * 64 + seg * 8);
        }
        __syncthreads();
#pragma unroll
        for (int dd = 0; dd < 2; ++dd) {
            if (dd < DKv[k]) {
                int d = S_[k] + dd;
#pragma unroll
                for (int ks = 0; ks < 2; ++ks) {
                    bf16x8 a = *(const bf16x8*)(arow + (size_t)d * 64 + ks * 32);
                    bf16x8 b = *(const bf16x8*)&sB[(w * 16 + lr) * 72 + ks * 32 + lk * 8];
                    acc[d] = __builtin_amdgcn_mfma_f32_16x16x32_bf16(a, b, acc[d], 0, 0, 0);
                }
            }
        }
    }

    int col = w * 16 + lr;
#pragma unroll
    for (int pp = 0; pp < 2; ++pp) {
        float2 v[12], o[12];
#pragma unroll
        for (int d = 0; d < 12; ++d) v[d] = make_float2(acc[d][pp * 2], acc[d][pp * 2 + 1]);
        act12p(qf, v, o);
        int row = bs0 + lk * 4 + pp * 2;
#pragma unroll
        for (int d = 0; d < 12; ++d) {
            t1c[((size_t)row * 12 + d) * 64 + col]       = f2bf(o[d].x);
            t1c[((size_t)(row + 1) * 12 + d) * 64 + col] = f2bf(o[d].y);
        }
    }
}

// ---------------- w3-GEMM + pe: A bf16 direct, h fp32 + hb bf16 ---------
__global__ __launch_bounds__(256) void k_lin4b(const unsigned short* __restrict__ t1c,
                                               const unsigned short* __restrict__ Wb,
                                               const float* __restrict__ qfp,
                                               const float* __restrict__ pe,
                                               float* __restrict__ h,
                                               unsigned short* __restrict__ hb) {
    const int d   = blockIdx.x;
    const int bs0 = blockIdx.y * 64;
    __shared__ unsigned short sB[64 * 72];
    const int t  = threadIdx.x;
    const int w  = t >> 6;
    const int l  = t & 63;
    const int lr = l & 15;
    const int lk = l >> 4;

    f32x4 acc[4];
#pragma unroll
    for (int f = 0; f < 4; ++f) acc[f] = (f32x4){0.f, 0.f, 0.f, 0.f};

    const unsigned short* wbase = Wb + (size_t)d_REP[d] * 64 * 64;
    const unsigned short* arow = t1c + ((size_t)(bs0 + w * 16 + lr) * 12 + d) * 64 + lk * 8;

    for (int e = t; e < 512; e += 256) {
        int c = e >> 3, seg = e & 7;
        *(bf16x8*)&sB[c * 72 + seg * 8] = *(const bf16x8*)(wbase + c * 64 + seg * 8);
    }
    __syncthreads();
#pragma unroll
    for (int ks = 0; ks < 2; ++ks) {
        bf16x8 a = *(const bf16x8*)(arow + ks * 32);
#pragma unroll
        for (int f = 0; f < 4; ++f) {
            bf16x8 b = *(const bf16x8*)&sB[(f * 16 + lr) * 72 + ks * 32 + lk * 8];
            acc[f] = __builtin_amdgcn_mfma_f32_16x16x32_bf16(a, b, acc[f], 0, 0, 0);
        }
    }

#pragma unroll
    for (int f = 0; f < 4; ++f) {
#pragma unroll
        for (int reg = 0; reg < 4; ++reg) {
            int bs = bs0 + w * 16 + lk * 4 + reg;
            int o  = f * 16 + lr;
            size_t row = (size_t)bs * 12 + d;
            float val = acc[f][reg] + qfp[144 + d] * pe[(bs & 511) * 64 + o];
            h[row * 64 + o] = val;
            hb[row * 64 + o] = f2bf(val);
        }
    }
}

// ---------------- wo-GEMM: A bf16 (attn out), B bf16, h +=, hb out ------
__global__ __launch_bounds__(256) void k_linwo(const unsigned short* __restrict__ t1b,
                                               const unsigned short* __restrict__ Wb,
                                               float* __restrict__ h,
                                               unsigned short* __restrict__ hb) {
    const int d   = blockIdx.x;
    const int bs0 = blockIdx.y * 64;
    __shared__ unsigned short sA[64 * 72];
    __shared__ unsigned short sB[64 * 72];
    const int t  = threadIdx.x;
    const int w  = t >> 6;
    const int l  = t & 63;
    const int lr = l & 15;
    const int lk = l >> 4;

    f32x4 acc[4];
#pragma unroll
    for (int f = 0; f < 4; ++f) acc[f] = (f32x4){0.f, 0.f, 0.f, 0.f};

    const unsigned short* wbase = Wb + (size_t)d_REP[d] * 64 * 64;

    for (int e = t; e < 512; e += 256) {
        int r = e >> 3, seg = e & 7;
        *(bf16x8*)&sA[r * 72 + seg * 8] =
            *(const bf16x8*)(t1b + ((size_t)(bs0 + r) * 12 + d) * 64 + seg * 8);
    }
    for (int e = t; e < 512; e += 256) {
        int c = e >> 3, seg = e & 7;
        *(bf16x8*)&sB[c * 72 + seg * 8] = *(const bf16x8*)(wbase + c * 64 + seg * 8);
    }
    __syncthreads();
#pragma unroll
    for (int ks = 0; ks < 2; ++ks) {
        bf16x8 a = *(const bf16x8*)&sA[(w * 16 + lr) * 72 + ks * 32 + lk * 8];
#pragma unroll
        for (int f = 0; f < 4; ++f) {
            bf16x8 b = *(const bf16x8*)&sB[(f * 16 + lr) * 72 + ks * 32 + lk * 8];
            acc[f] = __builtin_amdgcn_mfma_f32_16x16x32_bf16(a, b, acc[f], 0, 0, 0);
        }
    }

#pragma unroll
    for (int f = 0; f < 4; ++f) {
#pragma unroll
        for (int reg = 0; reg < 4; ++reg) {
            int bs = bs0 + w * 16 + lk * 4 + reg;
            int o  = f * 16 + lr;
            size_t row = (size_t)bs * 12 + d;
            float val = acc[f][reg] + h[row * 64 + o];
            h[row * 64 + o] = val;
            hb[row * 64 + o] = f2bf(val);
        }
    }
}

// ---------------- QKV projection (A = hb bf16, B bf16) ------------------
__global__ __launch_bounds__(256) void k_linqkv(const unsigned short* __restrict__ hbin,
                                                const unsigned short* __restrict__ wq,
                                                const unsigned short* __restrict__ wk,
                                                const unsigned short* __restrict__ wv,
                                                unsigned short* __restrict__ oq,
                                                unsigned short* __restrict__ ok,
                                                unsigned short* __restrict__ ov) {
    const int d   = blockIdx.x;
    const int bs0 = blockIdx.y * 64;
    __shared__ unsigned short sA[64 * 72];
    __shared__ unsigned short sB[64 * 72];
    const int t  = threadIdx.x;
    const int w  = t >> 6;
    const int l  = t & 63;
    const int lr = l & 15;
    const int lk = l >> 4;
    const int rep = d_REP[d];

    for (int e = t; e < 512; e += 256) {
        int r = e >> 3, seg = e & 7;
        *(bf16x8*)&sA[r * 72 + seg * 8] =
            *(const bf16x8*)(hbin + ((size_t)(bs0 + r) * 12 + d) * 64 + seg * 8);
    }

    for (int part = 0; part < 3; ++part) {
        const unsigned short* wsel = (part == 0) ? wq : (part == 1) ? wk : wv;
        const unsigned short* wbase = wsel + (size_t)rep * 64 * 64;
        __syncthreads();
        for (int e = t; e < 512; e += 256) {
            int c = e >> 3, seg = e & 7;
            *(bf16x8*)&sB[c * 72 + seg * 8] = *(const bf16x8*)(wbase + c * 64 + seg * 8);
        }
        __syncthreads();
        f32x4 acc[4];
#pragma unroll
        for (int f = 0; f < 4; ++f) acc[f] = (f32x4){0.f, 0.f, 0.f, 0.f};
#pragma unroll
        for (int ks = 0; ks < 2; ++ks) {
            bf16x8 a = *(const bf16x8*)&sA[(w * 16 + lr) * 72 + ks * 32 + lk * 8];
#pragma unroll
            for (int f = 0; f < 4; ++f) {
                bf16x8 b = *(const bf16x8*)&sB[(f * 16 + lr) * 72 + ks * 32 + lk * 8];
                acc[f] = __builtin_amdgcn_mfma_f32_16x16x32_bf16(a, b, acc[f], 0, 0, 0);
            }
        }
        unsigned short* oh = (part == 0) ? oq : (part == 1) ? ok : ov;
#pragma unroll
        for (int f = 0; f < 4; ++f) {
#pragma unroll
            for (int reg = 0; reg < 4; ++reg) {
                int bs = bs0 + w * 16 + lk * 4 + reg;
                int o  = f * 16 + lr;
                int b = bs >> 9, s = bs & 511;
                unsigned short hv = f2bf(acc[f][reg]);
                if (part < 2)
                    oh[(((size_t)(b * 8 + (o >> 3)) * 512 + s) * 96) + d * 8 + (o & 7)] = hv;
                else
                    oh[(((size_t)(b * 8 + (o >> 3)) * 96 + d * 8 + (o & 7)) * 512) + s] = hv;
            }
        }
    }
}

// ---------------- attention v7: 2-way split-K, 8 waves, 64 q-rows -------
#define SK_OFF 0                         // 2 x 64*104 ushort
#define SV_OFF (2 * 64 * 104)            // 2 x 96*72 ushort
#define PS_OFF (SV_OFF + 2 * 96 * 72)    // 8 x 16*72 ushort
__global__ __launch_bounds__(512) void k_attn7(const unsigned short* __restrict__ qh,
                                               const unsigned short* __restrict__ kh,
                                               const unsigned short* __restrict__ vt,
                                               unsigned short* __restrict__ out) {
    __shared__ unsigned short smem[PS_OFF + 8 * 16 * 72];   // 72704 B
    unsigned short* sK = smem + SK_OFF;
    unsigned short* sV = smem + SV_OFF;
    unsigned short* ps = smem + PS_OFF;
    const int bh = blockIdx.x >> 3;
    const int q0 = (blockIdx.x & 7) * 64;
    const int t = threadIdx.x;
    const int w = t >> 6;
    const int l = t & 63;
    const int lr = l & 15;
    const int lk = l >> 4;
    const int qg = w & 3;
    const int ks2 = w >> 2;

    const unsigned short* qgp = qh + ((size_t)bh * 512 + q0 + qg * 16) * 96;
    bf16x8 qa[3];
#pragma unroll
    for (int ks = 0; ks < 3; ++ks)
        qa[ks] = *(const bf16x8*)(qgp + (size_t)lr * 96 + ks * 32 + lk * 8);

    float ts[4] = {0.f, 0.f, 0.f, 0.f};
    f32x4 o[6];
#pragma unroll
    for (int f = 0; f < 6; ++f) o[f] = (f32x4){0.f, 0.f, 0.f, 0.f};

    const unsigned short* kg = kh + (size_t)bh * 512 * 96;
    const unsigned short* vg = vt + (size_t)bh * 96 * 512;
    const float scale = 0.10206207261596577f;   // 1/sqrt(96)

    for (int it = 0; it < 4; ++it) {
        __syncthreads();
        for (int e = t; e < 1536; e += 512) {
            int buf = e >= 768;
            int e2 = e - buf * 768;
            int row = e2 / 12, seg = e2 % 12;
            int tile = it + buf * 4;
            *(bf16x8*)&sK[buf * 64 * 104 + row * 104 + seg * 8] =
                *(const bf16x8*)(kg + ((size_t)(tile * 64 + row)) * 96 + seg * 8);
        }
        for (int e = t; e < 1536; e += 512) {
            int buf = e >= 768;
            int e2 = e - buf * 768;
            int row = e2 / 8, seg = e2 % 8;
            int tile = it + buf * 4;
            *(bf16x8*)&sV[buf * 96 * 72 + row * 72 + seg * 8] =
                *(const bf16x8*)(vg + (size_t)row * 512 + tile * 64 + seg * 8);
        }
        __syncthreads();

        const unsigned short* myK = sK + ks2 * 64 * 104;
        const unsigned short* myV = sV + ks2 * 96 * 72;

#pragma unroll
        for (int f = 0; f < 4; ++f) {
            f32x4 acc = {0.f, 0.f, 0.f, 0.f};
#pragma unroll
            for (int ks = 0; ks < 3; ++ks) {
                bf16x8 kb = *(const bf16x8*)&myK[(f * 16 + lr) * 104 + ks * 32 + lk * 8];
                acc = __builtin_amdgcn_mfma_f32_16x16x32_bf16(qa[ks], kb, acc, 0, 0, 0);
            }
#pragma unroll
            for (int r = 0; r < 4; ++r) {
                float p = __expf(acc[r] * scale);
                ts[r] += p;
                ps[w * 16 * 72 + (lk * 4 + r) * 72 + f * 16 + lr] = f2bf(p);
            }
        }

        bf16x8 pa[2];
#pragma unroll
        for (int ks = 0; ks < 2; ++ks)
            pa[ks] = *(const bf16x8*)&ps[w * 16 * 72 + lr * 72 + ks * 32 + lk * 8];
#pragma unroll
        for (int f = 0; f < 6; ++f) {
            f32x4 acc = o[f];
#pragma unroll
            for (int ks = 0; ks < 2; ++ks) {
                bf16x8 vb = *(const bf16x8*)&myV[(f * 16 + lr) * 72 + ks * 32 + lk * 8];
                acc = __builtin_amdgcn_mfma_f32_16x16x32_bf16(pa[ks], vb, acc, 0, 0, 0);
            }
            o[f] = acc;
        }
    }

    __syncthreads();
    float* cbuf = (float*)smem;                 // [4][64][29]
    if (ks2 == 1) {
        float* dst = cbuf + ((size_t)qg * 64 + l) * 29;
#pragma unroll
        for (int f = 0; f < 6; ++f) {
#pragma unroll
            for (int r = 0; r < 4; ++r) dst[f * 4 + r] = o[f][r];
        }
#pragma unroll
        for (int r = 0; r < 4; ++r) dst[24 + r] = ts[r];
    }
    __syncthreads();
    if (ks2 == 0) {
        const float* src = cbuf + ((size_t)qg * 64 + l) * 29;
#pragma unroll
        for (int f = 0; f < 6; ++f)
#pragma unroll
            for (int r = 0; r < 4; ++r) o[f][r] += src[f * 4 + r];
#pragma unroll
        for (int r = 0; r < 4; ++r) ts[r] += src[24 + r];

        float inv[4];
#pragma unroll
        for (int r = 0; r < 4; ++r) {
            float s2 = ts[r];
#pragma unroll
            for (int d = 1; d < 16; d <<= 1) s2 += __shfl_xor(s2, d);
            inv[r] = 1.0f / s2;
        }
        const int b = bh >> 3, hh = bh & 7;
#pragma unroll
        for (int r = 0; r < 4; ++r) {
            int s = q0 + qg * 16 + lk * 4 + r;
            unsigned short* ob = out + ((size_t)(b * 512 + s) * 12) * 64 + hh * 8;
#pragma unroll
            for (int f = 0; f < 6; ++f) {
                int col = f * 16 + lr;
                ob[(col >> 3) * 64 + (col & 7)] = f2bf(o[f][r] * inv[r]);
            }
        }
    }
}

// ---------------- fused f1-GEMM + act (packed) -> bf16 fmid -------------
__global__ __launch_bounds__(256, 4) void k_f1act(const unsigned short* __restrict__ hb,
                                                  const unsigned short* __restrict__ f1wb,
                                                  const float* __restrict__ qf,
                                                  unsigned short* __restrict__ fmidb) {
    constexpr int S_[7]  = {0, 1, 2, 4, 6, 8, 10};
    constexpr int DKv[7] = {1, 1, 2, 2, 2, 2, 2};
    const int bs0 = blockIdx.x * 16;
    const int c0  = blockIdx.y * 64;
    __shared__ unsigned short sB[64 * 72];
    const int t  = threadIdx.x;
    const int w  = t >> 6;
    const int l  = t & 63;
    const int lr = l & 15;
    const int lk = l >> 4;

    f32x4 acc[12];
#pragma unroll
    for (int d = 0; d < 12; ++d) acc[d] = (f32x4){0.f, 0.f, 0.f, 0.f};

    const unsigned short* arow = hb + (size_t)(bs0 + lr) * 12 * 64 + lk * 8;

#pragma unroll
    for (int k = 0; k < 7; ++k) {
        if (k) __syncthreads();
        const unsigned short* wbase = f1wb + ((size_t)k * 256 + c0) * 64;
        for (int e = t; e < 512; e += 256) {
            int c = e >> 3, seg = e & 7;
            *(bf16x8*)&sB[c * 72 + seg * 8] = *(const bf16x8*)(wbase + c * 64 + seg * 8);
        }
        __syncthreads();
#pragma unroll
        for (int dd = 0; dd < 2; ++dd) {
            if (dd < DKv[k]) {
                int d = S_[k] + dd;
#pragma unroll
                for (int ks = 0; ks < 2; ++ks) {
                    bf16x8 a = *(const bf16x8*)(arow + (size_t)d * 64 + ks * 32);
                    bf16x8 b = *(const bf16x8*)&sB[(w * 16 + lr) * 72 + ks * 32 + lk * 8];
                    acc[d] = __builtin_amdgcn_mfma_f32_16x16x32_bf16(a, b, acc[d], 0, 0, 0);
                }
            }
        }
    }

    int col = c0 + w * 16 + lr;
#pragma unroll
    for (int pp = 0; pp < 2; ++pp) {
        float2 v[12], o[12];
#pragma unroll
        for (int d = 0; d < 12; ++d) v[d] = make_float2(acc[d][pp * 2], acc[d][pp * 2 + 1]);
        act12p(qf, v, o);
        int row = bs0 + lk * 4 + pp * 2;
#pragma unroll
        for (int d = 0; d < 12; ++d) {
            fmidb[((size_t)row * 12 + d) * 256 + col]       = f2bf(o[d].x);
            fmidb[((size_t)(row + 1) * 12 + d) * 256 + col] = f2bf(o[d].y);
        }
    }
}

// ---------------- fused f2-GEMM (+res, h out) + next-layer QKV ----------
template <int QKV>
__global__ __launch_bounds__(256) void k_f2qkv(const unsigned short* __restrict__ inb,
                                               const unsigned short* __restrict__ Wf2,
                                               const unsigned short* __restrict__ wq,
                                               const unsigned short* __restrict__ wk,
                                               const unsigned short* __restrict__ wv,
                                               float* __restrict__ h,
                                               unsigned short* __restrict__ oq,
                                               unsigned short* __restrict__ ok,
                                               unsigned short* __restrict__ ov) {
    const int d   = blockIdx.x;
    const int bs0 = blockIdx.y * 64;
    __shared__ unsigned short sA[64 * 72];
    __shared__ unsigned short sB[64 * 72];
    __shared__ unsigned short sH[64 * 72];
    const int t  = threadIdx.x;
    const int w  = t >> 6;
    const int l  = t & 63;
    const int lr = l & 15;
    const int lk = l >> 4;
    const int rep = d_REP[d];

    f32x4 acc[4];
#pragma unroll
    for (int f = 0; f < 4; ++f) acc[f] = (f32x4){0.f, 0.f, 0.f, 0.f};

    const unsigned short* wbase = Wf2 + (size_t)rep * 64 * 256;

    for (int kc = 0; kc < 256; kc += 64) {
        __syncthreads();
        for (int e = t; e < 512; e += 256) {
            int r = e >> 3, seg = e & 7;
            *(bf16x8*)&sA[r * 72 + seg * 8] =
                *(const bf16x8*)(inb + ((size_t)(bs0 + r) * 12 + d) * 256 + kc + seg * 8);
        }
        for (int e = t; e < 512; e += 256) {
            int c = e >> 3, seg = e & 7;
            *(bf16x8*)&sB[c * 72 + seg * 8] =
                *(const bf16x8*)(wbase + (size_t)c * 256 + kc + seg * 8);
        }
        __syncthreads();
#pragma unroll
        for (int ks = 0; ks < 2; ++ks) {
            bf16x8 a = *(const bf16x8*)&sA[(w * 16 + lr) * 72 + ks * 32 + lk * 8];
#pragma unroll
            for (int f = 0; f < 4; ++f) {
                bf16x8 b = *(const bf16x8*)&sB[(f * 16 + lr) * 72 + ks * 32 + lk * 8];
                acc[f] = __builtin_amdgcn_mfma_f32_16x16x32_bf16(a, b, acc[f], 0, 0, 0);
            }
        }
    }

#pragma unroll
    for (int f = 0; f < 4; ++f) {
#pragma unroll
        for (int reg = 0; reg < 4; ++reg) {
            int rloc = w * 16 + lk * 4 + reg;
            int bs = bs0 + rloc;
            int o  = f * 16 + lr;
            size_t row = (size_t)bs * 12 + d;
            float val = acc[f][reg] + h[row * 64 + o];
            h[row * 64 + o] = val;
            if (QKV) sH[rloc * 72 + o] = f2bf(val);
        }
    }

    if (QKV) {
        for (int part = 0; part < 3; ++part) {
            const unsigned short* wsel = (part == 0) ? wq : (part == 1) ? wk : wv;
            const unsigned short* wb2 = wsel + (size_t)rep * 64 * 64;
            __syncthreads();
            for (int e = t; e < 512; e += 256) {
                int c = e >> 3, seg = e & 7;
                *(bf16x8*)&sB[c * 72 + seg * 8] = *(const bf16x8*)(wb2 + c * 64 + seg * 8);
            }
            __syncthreads();
            f32x4 a2[4];
#pragma unroll
            for (int f = 0; f < 4; ++f) a2[f] = (f32x4){0.f, 0.f, 0.f, 0.f};
#pragma unroll
            for (int ks = 0; ks < 2; ++ks) {
                bf16x8 a = *(const bf16x8*)&sH[(w * 16 + lr) * 72 + ks * 32 + lk * 8];
#pragma unroll
                for (int f = 0; f < 4; ++f) {
                    bf16x8 b = *(const bf16x8*)&sB[(f * 16 + lr) * 72 + ks * 32 + lk * 8];
                    a2[f] = __builtin_amdgcn_mfma_f32_16x16x32_bf16(a, b, a2[f], 0, 0, 0);
                }
            }
            unsigned short* oh = (part == 0) ? oq : (part == 1) ? ok : ov;
#pragma unroll
            for (int f = 0; f < 4; ++f) {
#pragma unroll
                for (int reg = 0; reg < 4; ++reg) {
                    int bs = bs0 + w * 16 + lk * 4 + reg;
                    int o  = f * 16 + lr;
                    int b = bs >> 9, s = bs & 511;
                    unsigned short hv = f2bf(a2[f][reg]);
                    if (part < 2)
                        oh[(((size_t)(b * 8 + (o >> 3)) * 512 + s) * 96) + d * 8 + (o & 7)] = hv;
                    else
                        oh[(((size_t)(b * 8 + (o >> 3)) * 96 + d * 8 + (o & 7)) * 512) + s] = hv;
                }
            }
        }
    }
}

// ---------------- fc_out (decoder tail) ----------------
__global__ void k_fcout(const float* __restrict__ h, const float* __restrict__ w,
                        const float* __restrict__ qf, float* __restrict__ z) {
    int bs = blockIdx.x;
    __shared__ float td[12];
    int t = threadIdx.x;
    if (t < 12) {
        const float* row = h + ((size_t)bs * 12 + t) * 64;
        const float* wr  = w + d_REP[t] * 64;
        float a = 0.f;
        for (int i = 0; i < 64; ++i) a += row[i] * wr[i];
        td[t] = a;
    }
    __syncthreads();
    if (t < 12) {
        float a = 0.f;
        for (int d = 0; d < 12; ++d) a += qf[d * 12 + t] * td[d];
        z[bs * 12 + t] = a / 7.0f;
    }
}

// ---------------- fused fc_out + VQ (encoder tail) ----------------------
__global__ __launch_bounds__(256) void k_fcvq(const float* __restrict__ h,
                                              const float* __restrict__ w,
                                              const float* __restrict__ qf,
                                              const float* __restrict__ cb,
                                              float* __restrict__ z,
                                              float* __restrict__ zvq,
                                              float* __restrict__ zst) {
    int bs = blockIdx.x;
    int t = threadIdx.x;
    __shared__ float td[12];
    __shared__ float zv[12];
    __shared__ float sb[256];
    __shared__ int   si[256];
    if (t < 12) {
        const float* row = h + ((size_t)bs * 12 + t) * 64;
        const float* wr  = w + d_REP[t] * 64;
        float a = 0.f;
        for (int i = 0; i < 64; ++i) a += row[i] * wr[i];
        td[t] = a;
    }
    __syncthreads();
    if (t < 12) {
        float a = 0.f;
        for (int d = 0; d < 12; ++d) a += qf[d * 12 + t] * td[d];
        a /= 7.0f;
        zv[t] = a;
        z[bs * 12 + t] = a;
    }
    __syncthreads();
    float zz = 0.f;
    for (int j = 0; j < 12; ++j) zz += zv[j] * zv[j];
    float best = 3.4e38f; int bi = 0x7fffffff;
    for (int c = t; c < KCB; c += 256) {
        const float* cr = cb + c * 12;
        float cc = 0.f, dot = 0.f;
        for (int j = 0; j < 12; ++j) { cc += cr[j] * cr[j]; dot += zv[j] * cr[j]; }
        float dist = zz + cc - 2.0f * dot;
        if (dist < best) { best = dist; bi = c; }
    }
    sb[t] = best; si[t] = bi; __syncthreads();
    for (int st = 128; st > 0; st >>= 1) {
        if (t < st) {
            if (sb[t + st] < sb[t] || (sb[t + st] == sb[t] && si[t + st] < si[t])) {
                sb[t] = sb[t + st]; si[t] = si[t + st];
            }
        }
        __syncthreads();
    }
    if (t < 12) {
        float c = cb[si[0] * 12 + t];
        zvq[bs * 12 + t] = c;
        float zi = zv[t];
        zst[bs * 12 + t] = (c - zi) + zi;
    }
}

// ---------------- merged losses ----------------
__global__ __launch_bounds__(256) void k_loss(const float* __restrict__ x,
                                              const float* __restrict__ logits,
                                              const float* __restrict__ z,
                                              const float* __restrict__ zvq,
                                              float* __restrict__ xr_out,
                                              float* __restrict__ p1,
                                              float* __restrict__ p2) {
    __shared__ float red[256];
    int t = threadIdx.x;
    float acc1 = 0.f, acc2 = 0.f;
    for (int i = blockIdx.x * 256 + t; i < NEL; i += gridDim.x * 256) {
        float lg = logits[i];
        float xr = 1.0f / (1.0f + expf(-lg));
        xr_out[i] = xr;
        float xi = x[i];
        float l1 = fmaxf(logf(xr), -100.0f);
        float l2 = fmaxf(logf(1.0f - xr), -100.0f);
        acc1 += xi * l1 + (1.0f - xi) * l2;
        float dd = zvq[i] - z[i];
        acc2 += dd * dd;
    }
    red[t] = acc1; __syncthreads();
    for (int st = 128; st > 0; st >>= 1) { if (t < st) red[t] += red[t + st]; __syncthreads(); }
    if (t == 0) p1[blockIdx.x] = red[0];
    __syncthreads();
    red[t] = acc2; __syncthreads();
    for (int st = 128; st > 0; st >>= 1) { if (t < st) red[t] += red[t + st]; __syncthreads(); }
    if (t == 0) p2[blockIdx.x] = red[0];
}

__global__ void k_final(const float* __restrict__ p1, const float* __restrict__ p2,
                        float* __restrict__ out) {
    if (threadIdx.x == 0) {
        float s1 = 0.f, s2 = 0.f;
        for (int i = 0; i < 96; ++i) { s1 += p1[i]; s2 += p2[i]; }
        out[NEL]     = -s1 / (float)NEL;
        out[NEL + 1] =  s2 / (float)NEL;
        out[NEL + 2] =  s2 / (float)NEL;
    }
}

// ------------------------------------------------------------------------
extern "C" void kernel_launch(void* const* d_in, const int* in_sizes, int n_in,
                              void* d_out, int out_size, void* d_ws, size_t ws_size,
                              hipStream_t stream) {
    const float* x   = (const float*)d_in[0];
    const float* efb = (const float*)d_in[1];
    const float* efw = (const float*)d_in[2];
    const float* ew1 = (const float*)d_in[3];
    const float* ew2 = (const float*)d_in[4];
    const float* ew3 = (const float*)d_in[5];
    const float* ewq = (const float*)d_in[6];
    const float* ewk = (const float*)d_in[7];
    const float* ewv = (const float*)d_in[8];
    const float* ewo = (const float*)d_in[9];
    const float* ef1 = (const float*)d_in[10];
    const float* ef2 = (const float*)d_in[11];
    const float* eow = (const float*)d_in[12];
    const float* cb  = (const float*)d_in[13];
    const float* dfb = (const float*)d_in[14];
    const float* dfw = (const float*)d_in[15];
    const float* dw1 = (const float*)d_in[16];
    const float* dw2 = (const float*)d_in[17];
    const float* dw3 = (const float*)d_in[18];
    const float* dwq = (const float*)d_in[19];
    const float* dwk = (const float*)d_in[20];
    const float* dwv = (const float*)d_in[21];
    const float* dwo = (const float*)d_in[22];
    const float* df1 = (const float*)d_in[23];
    const float* df2 = (const float*)d_in[24];
    const float* dow = (const float*)d_in[25];
    float* out = (float*)d_out;

    float* ws = (float*)d_ws;
    float* qf   = ws;                           // 512
    float* h    = ws + 512;                     // 3,145,728
    float* fmid = h + 3145728;                  // 12,582,912 region
    float* t1   = fmid + 12582912;              // 3,145,728 (bf16 eb / attn-out alias)
    float* z    = t1 + 3145728;
    float* zvq  = z + NEL;
    float* zst  = zvq + NEL;
    float* z2   = zst + NEL;
    float* p1   = z2 + NEL;
    float* p2   = p1 + 128;
    float* pe   = p2 + 128;                     // 32768
    unsigned short* wb = (unsigned short*)(pe + 32768);               // 1,433,600 ushorts
    unsigned short* hb = wb + WB_TOTAL;                               // 3,145,728 ushorts
    unsigned short* fmidb = (unsigned short*)fmid;                    // 12.6M ushorts
    unsigned short* t1c = fmidb;                                      // head tmp (dead before fmid use)
    unsigned short* q  = (unsigned short*)(fmid + 6291456);
    unsigned short* kk = q + 3145728;
    unsigned short* vv = kk + 3145728;
    unsigned short* t1b = (unsigned short*)t1;                        // eb / attn-out

    auto run_half = [&](const float* xin, const float* fb, const float* fw,
                        const float* w1, const float* w2, const float* w3,
                        const float* wq, const float* wk, const float* wv,
                        const float* wo, const float* f1, const float* f2) {
        k_cvtw<<<1400, 256, 0, stream>>>(w2, w3, wq, wk, wv, wo, f1, f2, wb);
        k_embact<<<BSN / 4, 256, 0, stream>>>(xin, fb, fw, w1, qf, t1b);
        k_w2act<<<256, 256, 0, stream>>>(t1b, wb + OB_W2, qf, t1c);
        k_lin4b<<<dim3(12, 64), 256, 0, stream>>>(t1c, wb + OB_W3, qf, pe, h, hb);
        k_linqkv<<<dim3(12, 64), 256, 0, stream>>>(hb, wb + OB_WQ, wb + OB_WK, wb + OB_WV, q, kk, vv);
        for (int l = 0; l < LLAY; ++l) {
            const unsigned short* wbo  = wb + OB_WO + (size_t)l * 28672;
            const unsigned short* wbf1 = wb + OB_F1 + (size_t)l * 114688;
            const unsigned short* wbf2 = wb + OB_F2 + (size_t)l * 114688;
            k_attn7<<<BB * HHEAD * 8, 512, 0, stream>>>(q, kk, vv, t1b);
            k_linwo<<<dim3(12, 64), 256, 0, stream>>>(t1b, wbo, h, hb);
            k_f1act<<<dim3(256, 4), 256, 0, stream>>>(hb, wbf1, qf, fmidb);
            if (l < LLAY - 1) {
                const unsigned short* wbq = wb + OB_WQ + (size_t)(l + 1) * 28672;
                const unsigned short* wbk = wb + OB_WK + (size_t)(l + 1) * 28672;
                const unsigned short* wbv = wb + OB_WV + (size_t)(l + 1) * 28672;
                k_f2qkv<1><<<dim3(12, 64), 256, 0, stream>>>(fmidb, wbf2, wbq, wbk, wbv, h, q, kk, vv);
            } else {
                k_f2qkv<0><<<dim3(12, 64), 256, 0, stream>>>(fmidb, wbf2, nullptr, nullptr, nullptr, h, nullptr, nullptr, nullptr);
            }
        }
    };

    k_init_qf<<<1, 256, 0, stream>>>(qf);
    k_init_pe<<<512, 64, 0, stream>>>(pe);
    run_half(x, efb, efw, ew1, ew2, ew3, ewq, ewk, ewv, ewo, ef1, ef2);
    k_fcvq<<<BSN, 256, 0, stream>>>(h, eow, qf, cb, z, zvq, zst);
    run_half(zst, dfb, dfw, dw1, dw2, dw3, dwq, dwk, dwv, dwo, df1, df2);
    k_fcout<<<BSN, 64, 0, stream>>>(h, dow, qf, z2);
    k_loss<<<96, 256, 0, stream>>>(x, z2, z, zvq, out, p1, p2);
    k_final<<<1, 64, 0, stream>>>(p1, p2, out);
}